// Round 2
// baseline (387.008 us; speedup 1.0000x reference)
//
#include <hip/hip_runtime.h>

#define T 2048
#define DIM 1024
#define NE 8
#define ED 2048
#define NSLOT (T * 2)
#define KSPLIT 2

#define BM 128
#define BN 128
#define BK 32
#define MAXWL 40

typedef __attribute__((ext_vector_type(8))) short s8v;   // 8 bf16 = 4 VGPRs
typedef __attribute__((ext_vector_type(4))) float f32x4; // MFMA C/D

__device__ __forceinline__ short f2bf(float f) {
    union { float f; unsigned u; } v;
    v.f = f;
    unsigned r = 0x7FFFu + ((v.u >> 16) & 1u);  // round-to-nearest-even
    v.u += r;
    return (short)(v.u >> 16);
}

__device__ __forceinline__ float bf2f(short s) {
    union { unsigned u; float f; } v;
    v.u = ((unsigned)(unsigned short)s) << 16;
    return v.f;
}

// pack two fp32 -> two bf16 (round-half-up) in 3 VALU: add 0x8000, perm high halves
__device__ __forceinline__ unsigned pkbf2(float lo, float hi) {
    union { float f; unsigned u; } a, b;
    a.f = lo; b.f = hi;
    return __builtin_amdgcn_perm(b.u + 0x8000u, a.u + 0x8000u, 0x07060302u);
}

// async global->LDS, 16B per lane; lds dst wave-uniform base, lane i -> base+16i
__device__ __forceinline__ void glds16(const void* g, void* l) {
    __builtin_amdgcn_global_load_lds(
        (const __attribute__((address_space(1))) void*)g,
        (__attribute__((address_space(3))) void*)l, 16, 0, 0);
}

// ---------------- weight convert: fp32 -> bf16, layout-preserving ----------------
__global__ __launch_bounds__(256) void convert_kernel(const float* __restrict__ src,
                                                      short* __restrict__ dst, int n8) {
    int stride = gridDim.x * 256;
    for (int i = blockIdx.x * 256 + threadIdx.x; i < n8; i += stride) {
        float4 a = ((const float4*)src)[2 * i];
        float4 b = ((const float4*)src)[2 * i + 1];
        uint4 o = { pkbf2(a.x, a.y), pkbf2(a.z, a.w), pkbf2(b.x, b.y), pkbf2(b.z, b.w) };
        ((uint4*)dst)[i] = o;
    }
}

// ---------------- router: 1 wave per token (also emits xb = bf16(x)) ----------------
__global__ void router_kernel(const float* __restrict__ x,
                              const float* __restrict__ gw,
                              const float* __restrict__ bias,
                              short* __restrict__ xb,
                              int* __restrict__ counts,
                              int* __restrict__ top2i,
                              float* __restrict__ top2w) {
    int wid = threadIdx.x >> 6;
    int lane = threadIdx.x & 63;
    int t = blockIdx.x * 4 + wid;

    const float* xr = x + (size_t)t * DIM + lane * 16;
    float4 xv[4];
#pragma unroll
    for (int j = 0; j < 4; ++j) xv[j] = *(const float4*)(xr + j * 4);

    s8v o0, o1;
#pragma unroll
    for (int j = 0; j < 2; ++j) {
        o0[j * 4 + 0] = f2bf(xv[j].x); o0[j * 4 + 1] = f2bf(xv[j].y);
        o0[j * 4 + 2] = f2bf(xv[j].z); o0[j * 4 + 3] = f2bf(xv[j].w);
        o1[j * 4 + 0] = f2bf(xv[j + 2].x); o1[j * 4 + 1] = f2bf(xv[j + 2].y);
        o1[j * 4 + 2] = f2bf(xv[j + 2].z); o1[j * 4 + 3] = f2bf(xv[j + 2].w);
    }
    *(s8v*)(xb + (size_t)t * DIM + lane * 16) = o0;
    *(s8v*)(xb + (size_t)t * DIM + lane * 16 + 8) = o1;

    float sc[NE];
#pragma unroll
    for (int e = 0; e < NE; ++e) {
        const float* gr = gw + e * DIM + lane * 16;
        float p = 0.f;
#pragma unroll
        for (int j = 0; j < 4; ++j) {
            float4 g = *(const float4*)(gr + j * 4);
            p += xv[j].x * g.x + xv[j].y * g.y + xv[j].z * g.z + xv[j].w * g.w;
        }
#pragma unroll
        for (int off = 32; off; off >>= 1) p += __shfl_xor(p, off, 64);
        sc[e] = 1.f / (1.f + __expf(-(p + bias[e])));
    }
    int b0 = 0; float s0 = sc[0];
#pragma unroll
    for (int e = 1; e < NE; ++e) if (sc[e] > s0) { s0 = sc[e]; b0 = e; }
    int b1 = -1; float s1 = -1e30f;
#pragma unroll
    for (int e = 0; e < NE; ++e) if (e != b0 && sc[e] > s1) { s1 = sc[e]; b1 = e; }
    float inv = 1.f / (s0 + s1 + 1e-6f);
    if (lane == 0) {
        top2i[t * 2 + 0] = b0; top2i[t * 2 + 1] = b1;
        top2w[t * 2 + 0] = s0 * inv; top2w[t * 2 + 1] = s1 * inv;
        atomicAdd(&counts[b0], 1);
        atomicAdd(&counts[b1], 1);
    }
}

// ---------------- plan: prefix + worklist + scatter ----------------
__global__ __launch_bounds__(256) void plan_kernel(
    const int* __restrict__ counts, const int* __restrict__ top2i,
    int* __restrict__ offsets, int* __restrict__ tok_list, int* __restrict__ slot_of,
    int* __restrict__ wl, int* __restrict__ nwl) {
    __shared__ int soff[NE];
    __shared__ int srun[NE];
    if (threadIdx.x == 0) {
        int a = 0;
        for (int e = 0; e < NE; ++e) { soff[e] = a; offsets[e] = a; a += counts[e]; srun[e] = 0; }
        int n = 0;
        for (int e = 0; e < NE; ++e) {
            int mt = (counts[e] + BM - 1) / BM;
            for (int m = 0; m < mt; ++m) wl[n++] = (e << 16) | m;
        }
        *nwl = n;
    }
    __syncthreads();
    for (int t = threadIdx.x; t < T; t += 256) {
#pragma unroll
        for (int k = 0; k < 2; ++k) {
            int e = top2i[t * 2 + k];
            int pos = atomicAdd(&srun[e], 1);
            int slot = soff[e] + pos;
            tok_list[slot] = t;
            slot_of[t * 2 + k] = slot;
        }
    }
}

// ---------------- grouped GEMM1: h = silu(x @ w1^T) ----------------
// BF=1: 4-buffer depth-3 pipeline, counted vmcnt(8), raw s_barrier.
// BF=0: original fp32 reg-pack dbuf path (fallback).
template <int BF>
__global__ __launch_bounds__(256) void ffn1_kernel(
    const short* __restrict__ xb, const float* __restrict__ w1,
    const short* __restrict__ wb,
    const int* __restrict__ counts, const int* __restrict__ offsets,
    const int* __restrict__ tok_list, const int* __restrict__ wl,
    const int* __restrict__ nwl, short* __restrict__ h) {
    int my = blockIdx.y;
    if (my >= *nwl) return;
    int e = wl[my] >> 16;
    int m0 = (wl[my] & 0xffff) * BM;
    int cnt = counts[e];
    int off = offsets[e];
    int n0 = blockIdx.x * BN;

    __shared__ __align__(16) short As[BF ? 4 : 2][4][BM][8];   // 32 KiB (BF)
    __shared__ __align__(16) short Bs[BF ? 4 : 2][4][BN][8];   // 32 KiB (BF)

    int tid = threadIdx.x;
    int lane = tid & 63, w = tid >> 6;
    int mo = (w >> 1) * 64, no = (w & 1) * 64;
    int lrow = lane & 15, lq = lane >> 4;

    f32x4 acc[4][4];
#pragma unroll
    for (int mi = 0; mi < 4; ++mi)
#pragma unroll
        for (int ni = 0; ni < 4; ++ni) acc[mi][ni] = (f32x4){0.f, 0.f, 0.f, 0.f};

    int ra0 = m0 + lane;      if (ra0 > cnt - 1) ra0 = cnt - 1;
    int ra1 = m0 + 64 + lane; if (ra1 > cnt - 1) ra1 = cnt - 1;
    const short* a0 = xb + (size_t)tok_list[off + ra0] * DIM + w * 8;
    const short* a1 = xb + (size_t)tok_list[off + ra1] * DIM + w * 8;

    const short* b0 = wb + ((size_t)e * ED + n0 + (w & 1) * 64 + lane) * DIM + (w >> 1) * 8;
    int br = tid >> 1, bq = tid & 1;
    const float* bp = w1 + ((size_t)e * ED + n0 + br) * DIM + bq * 16;

    const int NK = DIM / BK;   // 32

    if constexpr (BF) {
        // stage s -> buffer b
        auto stage = [&](int s, int b) {
            int k0 = s * BK;
            glds16(a0 + k0, &As[b][w][0][0]);
            glds16(a1 + k0, &As[b][w][64][0]);
            glds16(b0 + k0, &Bs[b][w >> 1][(w & 1) * 64][0]);
            glds16(b0 + k0 + 16, &Bs[b][2 + (w >> 1)][(w & 1) * 64][0]);
        };
        stage(0, 0); stage(1, 1); stage(2, 2);
        for (int kk = 0; kk < NK; ++kk) {
            // 12 glds outstanding (stages kk..kk+2); retire to 8 => stage kk landed.
            // memory-clobber asm: nothing crosses; barrier => all waves' stage kk landed.
            asm volatile("s_waitcnt vmcnt(8)\n\ts_barrier" ::: "memory");
            int cur = kk & 3;
            // buffer (kk+3)&3 was last read at iter kk-1 (reads retired before this
            // barrier), so overwriting is safe; clamp keeps vmcnt invariant at tail.
            int s = kk + 3 < NK ? kk + 3 : NK - 1;
            stage(s, (kk + 3) & 3);
            s8v af[4], bfr[4];
#pragma unroll
            for (int mi = 0; mi < 4; ++mi) af[mi] = *(const s8v*)&As[cur][lq][mo + mi * 16 + lrow][0];
#pragma unroll
            for (int ni = 0; ni < 4; ++ni) bfr[ni] = *(const s8v*)&Bs[cur][lq][no + ni * 16 + lrow][0];
#pragma unroll
            for (int mi = 0; mi < 4; ++mi)
#pragma unroll
                for (int ni = 0; ni < 4; ++ni)
                    acc[mi][ni] = __builtin_amdgcn_mfma_f32_16x16x32_bf16(af[mi], bfr[ni], acc[mi][ni], 0, 0, 0);
        }
    } else {
        float4 L0, L1, L2, L3;
        glds16(a0, &As[0][w][0][0]);
        glds16(a1, &As[0][w][64][0]);
        L0 = *(const float4*)(bp);     L1 = *(const float4*)(bp + 4);
        L2 = *(const float4*)(bp + 8); L3 = *(const float4*)(bp + 12);
        {
            uint4 p0 = { pkbf2(L0.x, L0.y), pkbf2(L0.z, L0.w), pkbf2(L1.x, L1.y), pkbf2(L1.z, L1.w) };
            uint4 p1 = { pkbf2(L2.x, L2.y), pkbf2(L2.z, L2.w), pkbf2(L3.x, L3.y), pkbf2(L3.z, L3.w) };
            *(uint4*)&Bs[0][2 * bq][br][0] = p0;
            *(uint4*)&Bs[0][2 * bq + 1][br][0] = p1;
        }
        L0 = *(const float4*)(bp + BK);     L1 = *(const float4*)(bp + BK + 4);
        L2 = *(const float4*)(bp + BK + 8); L3 = *(const float4*)(bp + BK + 12);
        for (int kk = 0; kk < NK; ++kk) {
            int cur = kk & 1, nxt = cur ^ 1;
            __syncthreads();
            if (kk + 1 < NK) {
                int k0 = (kk + 1) * BK;
                glds16(a0 + k0, &As[nxt][w][0][0]);
                glds16(a1 + k0, &As[nxt][w][64][0]);
                uint4 p0 = { pkbf2(L0.x, L0.y), pkbf2(L0.z, L0.w), pkbf2(L1.x, L1.y), pkbf2(L1.z, L1.w) };
                uint4 p1 = { pkbf2(L2.x, L2.y), pkbf2(L2.z, L2.w), pkbf2(L3.x, L3.y), pkbf2(L3.z, L3.w) };
                *(uint4*)&Bs[nxt][2 * bq][br][0] = p0;
                *(uint4*)&Bs[nxt][2 * bq + 1][br][0] = p1;
                if (kk + 2 < NK) {
                    const float* bpp = bp + (kk + 2) * BK;
                    L0 = *(const float4*)(bpp);     L1 = *(const float4*)(bpp + 4);
                    L2 = *(const float4*)(bpp + 8); L3 = *(const float4*)(bpp + 12);
                }
            }
            s8v af[4], bfr[4];
#pragma unroll
            for (int mi = 0; mi < 4; ++mi) af[mi] = *(const s8v*)&As[cur][lq][mo + mi * 16 + lrow][0];
#pragma unroll
            for (int ni = 0; ni < 4; ++ni) bfr[ni] = *(const s8v*)&Bs[cur][lq][no + ni * 16 + lrow][0];
#pragma unroll
            for (int mi = 0; mi < 4; ++mi)
#pragma unroll
                for (int ni = 0; ni < 4; ++ni)
                    acc[mi][ni] = __builtin_amdgcn_mfma_f32_16x16x32_bf16(af[mi], bfr[ni], acc[mi][ni], 0, 0, 0);
        }
    }

#pragma unroll
    for (int mi = 0; mi < 4; ++mi) {
#pragma unroll
        for (int ni = 0; ni < 4; ++ni) {
            int ln = n0 + no + ni * 16 + lrow;
#pragma unroll
            for (int r = 0; r < 4; ++r) {
                int row = m0 + mo + mi * 16 + lq * 4 + r;
                if (row < cnt) {
                    float v = acc[mi][ni][r];
                    v = v / (1.f + __expf(-v));  // silu
                    h[(size_t)(off + row) * ED + ln] = f2bf(v);
                }
            }
        }
    }
}

// ---------------- grouped GEMM2 (K-split): eo[ks][slot] = h @ w2^T[kchunk] ----------------
template <int BF>
__global__ __launch_bounds__(256) void ffn2_kernel(
    const short* __restrict__ h, const float* __restrict__ w2,
    const short* __restrict__ wb,
    const int* __restrict__ counts, const int* __restrict__ offsets,
    const int* __restrict__ wl, const int* __restrict__ nwl,
    short* __restrict__ eo) {
    int my = blockIdx.y;
    if (my >= *nwl) return;
    int e = wl[my] >> 16;
    int m0 = (wl[my] & 0xffff) * BM;
    int ksp = blockIdx.z;
    int cnt = counts[e];
    int off = offsets[e];
    int n0 = blockIdx.x * BN;
    const int kbase = ksp * (ED / KSPLIT);

    __shared__ __align__(16) short As[BF ? 4 : 2][4][BM][8];
    __shared__ __align__(16) short Bs[BF ? 4 : 2][4][BN][8];

    int tid = threadIdx.x;
    int lane = tid & 63, w = tid >> 6;
    int mo = (w >> 1) * 64, no = (w & 1) * 64;
    int lrow = lane & 15, lq = lane >> 4;

    f32x4 acc[4][4];
#pragma unroll
    for (int mi = 0; mi < 4; ++mi)
#pragma unroll
        for (int ni = 0; ni < 4; ++ni) acc[mi][ni] = (f32x4){0.f, 0.f, 0.f, 0.f};

    int ra0 = m0 + lane;      if (ra0 > cnt - 1) ra0 = cnt - 1;
    int ra1 = m0 + 64 + lane; if (ra1 > cnt - 1) ra1 = cnt - 1;
    const short* a0 = h + (size_t)(off + ra0) * ED + kbase + w * 8;
    const short* a1 = h + (size_t)(off + ra1) * ED + kbase + w * 8;

    const short* b0 = wb + ((size_t)e * DIM + n0 + (w & 1) * 64 + lane) * ED + kbase + (w >> 1) * 8;
    int br = tid >> 1, bq = tid & 1;
    const float* bp = w2 + ((size_t)e * DIM + n0 + br) * ED + kbase + bq * 16;

    const int NK = (ED / KSPLIT) / BK;   // 32

    if constexpr (BF) {
        auto stage = [&](int s, int b) {
            int k0 = s * BK;
            glds16(a0 + k0, &As[b][w][0][0]);
            glds16(a1 + k0, &As[b][w][64][0]);
            glds16(b0 + k0, &Bs[b][w >> 1][(w & 1) * 64][0]);
            glds16(b0 + k0 + 16, &Bs[b][2 + (w >> 1)][(w & 1) * 64][0]);
        };
        stage(0, 0); stage(1, 1); stage(2, 2);
        for (int kk = 0; kk < NK; ++kk) {
            asm volatile("s_waitcnt vmcnt(8)\n\ts_barrier" ::: "memory");
            int cur = kk & 3;
            int s = kk + 3 < NK ? kk + 3 : NK - 1;
            stage(s, (kk + 3) & 3);
            s8v af[4], bfr[4];
#pragma unroll
            for (int mi = 0; mi < 4; ++mi) af[mi] = *(const s8v*)&As[cur][lq][mo + mi * 16 + lrow][0];
#pragma unroll
            for (int ni = 0; ni < 4; ++ni) bfr[ni] = *(const s8v*)&Bs[cur][lq][no + ni * 16 + lrow][0];
#pragma unroll
            for (int mi = 0; mi < 4; ++mi)
#pragma unroll
                for (int ni = 0; ni < 4; ++ni)
                    acc[mi][ni] = __builtin_amdgcn_mfma_f32_16x16x32_bf16(af[mi], bfr[ni], acc[mi][ni], 0, 0, 0);
        }
    } else {
        float4 L0, L1, L2, L3;
        glds16(a0, &As[0][w][0][0]);
        glds16(a1, &As[0][w][64][0]);
        L0 = *(const float4*)(bp);     L1 = *(const float4*)(bp + 4);
        L2 = *(const float4*)(bp + 8); L3 = *(const float4*)(bp + 12);
        {
            uint4 p0 = { pkbf2(L0.x, L0.y), pkbf2(L0.z, L0.w), pkbf2(L1.x, L1.y), pkbf2(L1.z, L1.w) };
            uint4 p1 = { pkbf2(L2.x, L2.y), pkbf2(L2.z, L2.w), pkbf2(L3.x, L3.y), pkbf2(L3.z, L3.w) };
            *(uint4*)&Bs[0][2 * bq][br][0] = p0;
            *(uint4*)&Bs[0][2 * bq + 1][br][0] = p1;
        }
        L0 = *(const float4*)(bp + BK);     L1 = *(const float4*)(bp + BK + 4);
        L2 = *(const float4*)(bp + BK + 8); L3 = *(const float4*)(bp + BK + 12);
        for (int kk = 0; kk < NK; ++kk) {
            int cur = kk & 1, nxt = cur ^ 1;
            __syncthreads();
            if (kk + 1 < NK) {
                int k0 = (kk + 1) * BK;
                glds16(a0 + k0, &As[nxt][w][0][0]);
                glds16(a1 + k0, &As[nxt][w][64][0]);
                uint4 p0 = { pkbf2(L0.x, L0.y), pkbf2(L0.z, L0.w), pkbf2(L1.x, L1.y), pkbf2(L1.z, L1.w) };
                uint4 p1 = { pkbf2(L2.x, L2.y), pkbf2(L2.z, L2.w), pkbf2(L3.x, L3.y), pkbf2(L3.z, L3.w) };
                *(uint4*)&Bs[nxt][2 * bq][br][0] = p0;
                *(uint4*)&Bs[nxt][2 * bq + 1][br][0] = p1;
                if (kk + 2 < NK) {
                    const float* bpp = bp + (kk + 2) * BK;
                    L0 = *(const float4*)(bpp);     L1 = *(const float4*)(bpp + 4);
                    L2 = *(const float4*)(bpp + 8); L3 = *(const float4*)(bpp + 12);
                }
            }
            s8v af[4], bfr[4];
#pragma unroll
            for (int mi = 0; mi < 4; ++mi) af[mi] = *(const s8v*)&As[cur][lq][mo + mi * 16 + lrow][0];
#pragma unroll
            for (int ni = 0; ni < 4; ++ni) bfr[ni] = *(const s8v*)&Bs[cur][lq][no + ni * 16 + lrow][0];
#pragma unroll
            for (int mi = 0; mi < 4; ++mi)
#pragma unroll
                for (int ni = 0; ni < 4; ++ni)
                    acc[mi][ni] = __builtin_amdgcn_mfma_f32_16x16x32_bf16(af[mi], bfr[ni], acc[mi][ni], 0, 0, 0);
        }
    }

    short* eop = eo + (size_t)ksp * NSLOT * DIM;
#pragma unroll
    for (int mi = 0; mi < 4; ++mi) {
#pragma unroll
        for (int ni = 0; ni < 4; ++ni) {
            int ln = n0 + no + ni * 16 + lrow;
#pragma unroll
            for (int r = 0; r < 4; ++r) {
                int row = m0 + mo + mi * 16 + lq * 4 + r;
                if (row < cnt) {
                    eop[(size_t)(off + row) * DIM + ln] = f2bf(acc[mi][ni][r]);
                }
            }
        }
    }
}

// ---------------- combine ----------------
__global__ __launch_bounds__(256) void combine_kernel(
    const short* __restrict__ eo, const int* __restrict__ slot_of,
    const float* __restrict__ top2w, float* __restrict__ out) {
    int idx = blockIdx.x * 256 + threadIdx.x;
    int t = idx >> 7;
    int c = idx & 127;
    int s0 = slot_of[2 * t], s1 = slot_of[2 * t + 1];
    float w0 = top2w[2 * t], w1 = top2w[2 * t + 1];
    const short* e0 = eo;
    const short* e1 = eo + (size_t)NSLOT * DIM;
    s8v a0 = *(const s8v*)(e0 + (size_t)s0 * DIM + c * 8);
    s8v a1 = *(const s8v*)(e1 + (size_t)s0 * DIM + c * 8);
    s8v b0 = *(const s8v*)(e0 + (size_t)s1 * DIM + c * 8);
    s8v b1 = *(const s8v*)(e1 + (size_t)s1 * DIM + c * 8);
    float4 o[2];
#pragma unroll
    for (int j = 0; j < 8; ++j) {
        float v = w0 * (bf2f(a0[j]) + bf2f(a1[j])) + w1 * (bf2f(b0[j]) + bf2f(b1[j]));
        ((float*)o)[j] = v;
    }
    float4* op = (float4*)(out + (size_t)t * DIM + c * 8);
    op[0] = o[0];
    op[1] = o[1];
}

extern "C" void kernel_launch(void* const* d_in, const int* in_sizes, int n_in,
                              void* d_out, int out_size, void* d_ws, size_t ws_size,
                              hipStream_t stream) {
    const float* x    = (const float*)d_in[0];
    const float* gw   = (const float*)d_in[1];
    const float* bias = (const float*)d_in[2];
    const float* w1   = (const float*)d_in[3];
    const float* w2   = (const float*)d_in[4];
    float* out = (float*)d_out;

    char* ws = (char*)d_ws;
    short* xb = (short*)ws;                           // 4 MiB  [T][DIM] bf16
    short* h  = (short*)(ws + (4ull << 20));          // 16 MiB [NSLOT][ED] bf16
    short* eo = (short*)(ws + (20ull << 20));         // 16 MiB [2][NSLOT][DIM] bf16
    char* meta = ws + (36ull << 20);
    int*   counts   = (int*)(meta);                   // [8]
    int*   offsets  = (int*)(meta + 64);              // [8]
    int*   tok_list = (int*)(meta + 128);             // [NSLOT]
    int*   slot_of  = (int*)(meta + 128 + 4 * NSLOT); // [T*2]
    int*   top2i    = (int*)(meta + 128 + 8 * NSLOT); // [T*2]
    float* top2w    = (float*)(meta + 128 + 8 * NSLOT + 8 * T);
    int*   wl       = (int*)(meta + 128 + 8 * NSLOT + 16 * T);   // [MAXWL]
    int*   nwl      = (int*)(meta + 128 + 8 * NSLOT + 16 * T + 4 * MAXWL);
    short* wb       = (short*)(ws + (37ull << 20));   // 32 MiB bf16 weight buffer (shared w1/w2)

    // need 37 MiB + 32 MiB for the bf16-weight path
    bool bf = ws_size >= (70ull << 20);

    hipMemsetAsync(counts, 0, 32, stream);

    if (bf) {
        convert_kernel<<<2048, 256, 0, stream>>>(w1, wb, NE * ED * DIM / 8);
    }
    router_kernel<<<T / 4, 256, 0, stream>>>(x, gw, bias, xb, counts, top2i, top2w);
    plan_kernel<<<1, 256, 0, stream>>>(counts, top2i, offsets, tok_list, slot_of, wl, nwl);
    if (bf) {
        ffn1_kernel<1><<<dim3(ED / BN, MAXWL), 256, 0, stream>>>(xb, w1, wb, counts, offsets, tok_list, wl, nwl, h);
        convert_kernel<<<2048, 256, 0, stream>>>(w2, wb, NE * DIM * ED / 8);
        ffn2_kernel<1><<<dim3(DIM / BN, MAXWL, KSPLIT), 256, 0, stream>>>(h, w2, wb, counts, offsets, wl, nwl, eo);
    } else {
        ffn1_kernel<0><<<dim3(ED / BN, MAXWL), 256, 0, stream>>>(xb, w1, nullptr, counts, offsets, tok_list, wl, nwl, h);
        ffn2_kernel<0><<<dim3(DIM / BN, MAXWL, KSPLIT), 256, 0, stream>>>(h, w2, nullptr, counts, offsets, wl, nwl, eo);
    }
    combine_kernel<<<T * DIM / 8 / 256, 256, 0, stream>>>(eo, slot_of, top2w, out);
}

// Round 3
// 381.135 us; speedup vs baseline: 1.0154x; 1.0154x over previous
//
#include <hip/hip_runtime.h>

#define T 2048
#define DIM 1024
#define NE 8
#define ED 2048
#define NSLOT (T * 2)
#define KSPLIT 2

#define BM 128
#define BN 128
#define BK 32
#define MAXWL 40

typedef __attribute__((ext_vector_type(8))) short s8v;   // 8 bf16 = 4 VGPRs
typedef __attribute__((ext_vector_type(4))) float f32x4; // MFMA C/D

__device__ __forceinline__ short f2bf(float f) {
    union { float f; unsigned u; } v;
    v.f = f;
    unsigned r = 0x7FFFu + ((v.u >> 16) & 1u);  // round-to-nearest-even
    v.u += r;
    return (short)(v.u >> 16);
}

__device__ __forceinline__ float bf2f(short s) {
    union { unsigned u; float f; } v;
    v.u = ((unsigned)(unsigned short)s) << 16;
    return v.f;
}

// pack two fp32 -> two bf16 (round-half-up) in 3 VALU: add 0x8000, perm high halves
__device__ __forceinline__ unsigned pkbf2(float lo, float hi) {
    union { float f; unsigned u; } a, b;
    a.f = lo; b.f = hi;
    return __builtin_amdgcn_perm(b.u + 0x8000u, a.u + 0x8000u, 0x07060302u);
}

// async global->LDS, 16B per lane; lds dst wave-uniform base, lane i -> base+16i
__device__ __forceinline__ void glds16(const void* g, void* l) {
    __builtin_amdgcn_global_load_lds(
        (const __attribute__((address_space(1))) void*)g,
        (__attribute__((address_space(3))) void*)l, 16, 0, 0);
}

// ---------------- weight convert: fp32 -> bf16, layout-preserving ----------------
__global__ __launch_bounds__(256) void convert_kernel(const float* __restrict__ src,
                                                      short* __restrict__ dst, int n8) {
    int stride = gridDim.x * 256;
    for (int i = blockIdx.x * 256 + threadIdx.x; i < n8; i += stride) {
        float4 a = ((const float4*)src)[2 * i];
        float4 b = ((const float4*)src)[2 * i + 1];
        uint4 o = { pkbf2(a.x, a.y), pkbf2(a.z, a.w), pkbf2(b.x, b.y), pkbf2(b.z, b.w) };
        ((uint4*)dst)[i] = o;
    }
}

// ---------------- router: 1 wave per token (also emits xb = bf16(x)) ----------------
__global__ void router_kernel(const float* __restrict__ x,
                              const float* __restrict__ gw,
                              const float* __restrict__ bias,
                              short* __restrict__ xb,
                              int* __restrict__ counts,
                              int* __restrict__ top2i,
                              float* __restrict__ top2w) {
    int wid = threadIdx.x >> 6;
    int lane = threadIdx.x & 63;
    int t = blockIdx.x * 4 + wid;

    const float* xr = x + (size_t)t * DIM + lane * 16;
    float4 xv[4];
#pragma unroll
    for (int j = 0; j < 4; ++j) xv[j] = *(const float4*)(xr + j * 4);

    s8v o0, o1;
#pragma unroll
    for (int j = 0; j < 2; ++j) {
        o0[j * 4 + 0] = f2bf(xv[j].x); o0[j * 4 + 1] = f2bf(xv[j].y);
        o0[j * 4 + 2] = f2bf(xv[j].z); o0[j * 4 + 3] = f2bf(xv[j].w);
        o1[j * 4 + 0] = f2bf(xv[j + 2].x); o1[j * 4 + 1] = f2bf(xv[j + 2].y);
        o1[j * 4 + 2] = f2bf(xv[j + 2].z); o1[j * 4 + 3] = f2bf(xv[j + 2].w);
    }
    *(s8v*)(xb + (size_t)t * DIM + lane * 16) = o0;
    *(s8v*)(xb + (size_t)t * DIM + lane * 16 + 8) = o1;

    float sc[NE];
#pragma unroll
    for (int e = 0; e < NE; ++e) {
        const float* gr = gw + e * DIM + lane * 16;
        float p = 0.f;
#pragma unroll
        for (int j = 0; j < 4; ++j) {
            float4 g = *(const float4*)(gr + j * 4);
            p += xv[j].x * g.x + xv[j].y * g.y + xv[j].z * g.z + xv[j].w * g.w;
        }
#pragma unroll
        for (int off = 32; off; off >>= 1) p += __shfl_xor(p, off, 64);
        sc[e] = 1.f / (1.f + __expf(-(p + bias[e])));
    }
    int b0 = 0; float s0 = sc[0];
#pragma unroll
    for (int e = 1; e < NE; ++e) if (sc[e] > s0) { s0 = sc[e]; b0 = e; }
    int b1 = -1; float s1 = -1e30f;
#pragma unroll
    for (int e = 0; e < NE; ++e) if (e != b0 && sc[e] > s1) { s1 = sc[e]; b1 = e; }
    float inv = 1.f / (s0 + s1 + 1e-6f);
    if (lane == 0) {
        top2i[t * 2 + 0] = b0; top2i[t * 2 + 1] = b1;
        top2w[t * 2 + 0] = s0 * inv; top2w[t * 2 + 1] = s1 * inv;
        atomicAdd(&counts[b0], 1);
        atomicAdd(&counts[b1], 1);
    }
}

// ---------------- plan: prefix + worklist + scatter ----------------
__global__ __launch_bounds__(256) void plan_kernel(
    const int* __restrict__ counts, const int* __restrict__ top2i,
    int* __restrict__ offsets, int* __restrict__ tok_list, int* __restrict__ slot_of,
    int* __restrict__ wl, int* __restrict__ nwl) {
    __shared__ int soff[NE];
    __shared__ int srun[NE];
    if (threadIdx.x == 0) {
        int a = 0;
        for (int e = 0; e < NE; ++e) { soff[e] = a; offsets[e] = a; a += counts[e]; srun[e] = 0; }
        int n = 0;
        for (int e = 0; e < NE; ++e) {
            int mt = (counts[e] + BM - 1) / BM;
            for (int m = 0; m < mt; ++m) wl[n++] = (e << 16) | m;
        }
        *nwl = n;
    }
    __syncthreads();
    for (int t = threadIdx.x; t < T; t += 256) {
#pragma unroll
        for (int k = 0; k < 2; ++k) {
            int e = top2i[t * 2 + k];
            int pos = atomicAdd(&srun[e], 1);
            int slot = soff[e] + pos;
            tok_list[slot] = t;
            slot_of[t * 2 + k] = slot;
        }
    }
}

// ---------------- grouped GEMM1: h = silu(x @ w1^T) ----------------
// BF=1: BK=64 double-buffer, single __syncthreads per K-step (16 steps).
// BF=0: original fp32 reg-pack dbuf path, BK=32 (fallback).
template <int BF>
__global__ __launch_bounds__(256) void ffn1_kernel(
    const short* __restrict__ xb, const float* __restrict__ w1,
    const short* __restrict__ wb,
    const int* __restrict__ counts, const int* __restrict__ offsets,
    const int* __restrict__ tok_list, const int* __restrict__ wl,
    const int* __restrict__ nwl, short* __restrict__ h) {
    int my = blockIdx.y;
    if (my >= *nwl) return;
    int e = wl[my] >> 16;
    int m0 = (wl[my] & 0xffff) * BM;
    int cnt = counts[e];
    int off = offsets[e];
    int n0 = blockIdx.x * BN;

    constexpr int KQ = BF ? 8 : 4;               // k-planes per buffer
    __shared__ __align__(16) short As[2][KQ][BM][8];   // BF: 32 KiB
    __shared__ __align__(16) short Bs[2][KQ][BN][8];   // BF: 32 KiB

    int tid = threadIdx.x;
    int lane = tid & 63, w = tid >> 6;
    int mo = (w >> 1) * 64, no = (w & 1) * 64;
    int lrow = lane & 15, lq = lane >> 4;

    f32x4 acc[4][4];
#pragma unroll
    for (int mi = 0; mi < 4; ++mi)
#pragma unroll
        for (int ni = 0; ni < 4; ++ni) acc[mi][ni] = (f32x4){0.f, 0.f, 0.f, 0.f};

    int ra0 = m0 + lane;      if (ra0 > cnt - 1) ra0 = cnt - 1;
    int ra1 = m0 + 64 + lane; if (ra1 > cnt - 1) ra1 = cnt - 1;
    const short* a0 = xb + (size_t)tok_list[off + ra0] * DIM + w * 8;
    const short* a1 = xb + (size_t)tok_list[off + ra1] * DIM + w * 8;

    const short* b0 = wb + ((size_t)e * ED + n0 + (w & 1) * 64 + lane) * DIM + (w >> 1) * 8;
    int br = tid >> 1, bq = tid & 1;
    const float* bp = w1 + ((size_t)e * ED + n0 + br) * DIM + bq * 16;

    if constexpr (BF) {
        const int NK = DIM / 64;   // 16
        int q = w >> 1, rh = (w & 1) * 64;
        // stage K-step s (64 wide) into buffer b: 8 glds16/wave
        auto stage = [&](int s, int b) {
            int k0 = s * 64;
            glds16(a0 + k0,      &As[b][w][0][0]);
            glds16(a1 + k0,      &As[b][w][64][0]);
            glds16(a0 + k0 + 32, &As[b][w + 4][0][0]);
            glds16(a1 + k0 + 32, &As[b][w + 4][64][0]);
            glds16(b0 + k0,      &Bs[b][q][rh][0]);
            glds16(b0 + k0 + 16, &Bs[b][q + 2][rh][0]);
            glds16(b0 + k0 + 32, &Bs[b][q + 4][rh][0]);
            glds16(b0 + k0 + 48, &Bs[b][q + 6][rh][0]);
        };
        stage(0, 0);
        for (int kk = 0; kk < NK; ++kk) {
            int cur = kk & 1, nxt = cur ^ 1;
            __syncthreads();   // drains: buf[cur] landed everywhere
            if (kk + 1 < NK) stage(kk + 1, nxt);
            s8v af[2][4], bfr[2][4];
#pragma unroll
            for (int ks = 0; ks < 2; ++ks) {
#pragma unroll
                for (int mi = 0; mi < 4; ++mi)
                    af[ks][mi] = *(const s8v*)&As[cur][ks * 4 + lq][mo + mi * 16 + lrow][0];
#pragma unroll
                for (int ni = 0; ni < 4; ++ni)
                    bfr[ks][ni] = *(const s8v*)&Bs[cur][ks * 4 + lq][no + ni * 16 + lrow][0];
            }
#pragma unroll
            for (int ks = 0; ks < 2; ++ks)
#pragma unroll
                for (int mi = 0; mi < 4; ++mi)
#pragma unroll
                    for (int ni = 0; ni < 4; ++ni)
                        acc[mi][ni] = __builtin_amdgcn_mfma_f32_16x16x32_bf16(af[ks][mi], bfr[ks][ni], acc[mi][ni], 0, 0, 0);
        }
    } else {
        const int NK = DIM / BK;   // 32
        float4 L0, L1, L2, L3;
        glds16(a0, &As[0][w][0][0]);
        glds16(a1, &As[0][w][64][0]);
        L0 = *(const float4*)(bp);     L1 = *(const float4*)(bp + 4);
        L2 = *(const float4*)(bp + 8); L3 = *(const float4*)(bp + 12);
        {
            uint4 p0 = { pkbf2(L0.x, L0.y), pkbf2(L0.z, L0.w), pkbf2(L1.x, L1.y), pkbf2(L1.z, L1.w) };
            uint4 p1 = { pkbf2(L2.x, L2.y), pkbf2(L2.z, L2.w), pkbf2(L3.x, L3.y), pkbf2(L3.z, L3.w) };
            *(uint4*)&Bs[0][2 * bq][br][0] = p0;
            *(uint4*)&Bs[0][2 * bq + 1][br][0] = p1;
        }
        L0 = *(const float4*)(bp + BK);     L1 = *(const float4*)(bp + BK + 4);
        L2 = *(const float4*)(bp + BK + 8); L3 = *(const float4*)(bp + BK + 12);
        for (int kk = 0; kk < NK; ++kk) {
            int cur = kk & 1, nxt = cur ^ 1;
            __syncthreads();
            if (kk + 1 < NK) {
                int k0 = (kk + 1) * BK;
                glds16(a0 + k0, &As[nxt][w][0][0]);
                glds16(a1 + k0, &As[nxt][w][64][0]);
                uint4 p0 = { pkbf2(L0.x, L0.y), pkbf2(L0.z, L0.w), pkbf2(L1.x, L1.y), pkbf2(L1.z, L1.w) };
                uint4 p1 = { pkbf2(L2.x, L2.y), pkbf2(L2.z, L2.w), pkbf2(L3.x, L3.y), pkbf2(L3.z, L3.w) };
                *(uint4*)&Bs[nxt][2 * bq][br][0] = p0;
                *(uint4*)&Bs[nxt][2 * bq + 1][br][0] = p1;
                if (kk + 2 < NK) {
                    const float* bpp = bp + (kk + 2) * BK;
                    L0 = *(const float4*)(bpp);     L1 = *(const float4*)(bpp + 4);
                    L2 = *(const float4*)(bpp + 8); L3 = *(const float4*)(bpp + 12);
                }
            }
            s8v af[4], bfr[4];
#pragma unroll
            for (int mi = 0; mi < 4; ++mi) af[mi] = *(const s8v*)&As[cur][lq][mo + mi * 16 + lrow][0];
#pragma unroll
            for (int ni = 0; ni < 4; ++ni) bfr[ni] = *(const s8v*)&Bs[cur][lq][no + ni * 16 + lrow][0];
#pragma unroll
            for (int mi = 0; mi < 4; ++mi)
#pragma unroll
                for (int ni = 0; ni < 4; ++ni)
                    acc[mi][ni] = __builtin_amdgcn_mfma_f32_16x16x32_bf16(af[mi], bfr[ni], acc[mi][ni], 0, 0, 0);
        }
    }

#pragma unroll
    for (int mi = 0; mi < 4; ++mi) {
#pragma unroll
        for (int ni = 0; ni < 4; ++ni) {
            int ln = n0 + no + ni * 16 + lrow;
#pragma unroll
            for (int r = 0; r < 4; ++r) {
                int row = m0 + mo + mi * 16 + lq * 4 + r;
                if (row < cnt) {
                    float v = acc[mi][ni][r];
                    v = v / (1.f + __expf(-v));  // silu
                    h[(size_t)(off + row) * ED + ln] = f2bf(v);
                }
            }
        }
    }
}

// ---------------- grouped GEMM2 (K-split): eo[ks][slot] = h @ w2^T[kchunk] ----------------
template <int BF>
__global__ __launch_bounds__(256) void ffn2_kernel(
    const short* __restrict__ h, const float* __restrict__ w2,
    const short* __restrict__ wb,
    const int* __restrict__ counts, const int* __restrict__ offsets,
    const int* __restrict__ wl, const int* __restrict__ nwl,
    short* __restrict__ eo) {
    int my = blockIdx.y;
    if (my >= *nwl) return;
    int e = wl[my] >> 16;
    int m0 = (wl[my] & 0xffff) * BM;
    int ksp = blockIdx.z;
    int cnt = counts[e];
    int off = offsets[e];
    int n0 = blockIdx.x * BN;
    const int kbase = ksp * (ED / KSPLIT);

    constexpr int KQ = BF ? 8 : 4;
    __shared__ __align__(16) short As[2][KQ][BM][8];
    __shared__ __align__(16) short Bs[2][KQ][BN][8];

    int tid = threadIdx.x;
    int lane = tid & 63, w = tid >> 6;
    int mo = (w >> 1) * 64, no = (w & 1) * 64;
    int lrow = lane & 15, lq = lane >> 4;

    f32x4 acc[4][4];
#pragma unroll
    for (int mi = 0; mi < 4; ++mi)
#pragma unroll
        for (int ni = 0; ni < 4; ++ni) acc[mi][ni] = (f32x4){0.f, 0.f, 0.f, 0.f};

    int ra0 = m0 + lane;      if (ra0 > cnt - 1) ra0 = cnt - 1;
    int ra1 = m0 + 64 + lane; if (ra1 > cnt - 1) ra1 = cnt - 1;
    const short* a0 = h + (size_t)(off + ra0) * ED + kbase + w * 8;
    const short* a1 = h + (size_t)(off + ra1) * ED + kbase + w * 8;

    const short* b0 = wb + ((size_t)e * DIM + n0 + (w & 1) * 64 + lane) * ED + kbase + (w >> 1) * 8;
    int br = tid >> 1, bq = tid & 1;
    const float* bp = w2 + ((size_t)e * DIM + n0 + br) * ED + kbase + bq * 16;

    if constexpr (BF) {
        const int NK = (ED / KSPLIT) / 64;   // 16
        int q = w >> 1, rh = (w & 1) * 64;
        auto stage = [&](int s, int b) {
            int k0 = s * 64;
            glds16(a0 + k0,      &As[b][w][0][0]);
            glds16(a1 + k0,      &As[b][w][64][0]);
            glds16(a0 + k0 + 32, &As[b][w + 4][0][0]);
            glds16(a1 + k0 + 32, &As[b][w + 4][64][0]);
            glds16(b0 + k0,      &Bs[b][q][rh][0]);
            glds16(b0 + k0 + 16, &Bs[b][q + 2][rh][0]);
            glds16(b0 + k0 + 32, &Bs[b][q + 4][rh][0]);
            glds16(b0 + k0 + 48, &Bs[b][q + 6][rh][0]);
        };
        stage(0, 0);
        for (int kk = 0; kk < NK; ++kk) {
            int cur = kk & 1, nxt = cur ^ 1;
            __syncthreads();
            if (kk + 1 < NK) stage(kk + 1, nxt);
            s8v af[2][4], bfr[2][4];
#pragma unroll
            for (int ks = 0; ks < 2; ++ks) {
#pragma unroll
                for (int mi = 0; mi < 4; ++mi)
                    af[ks][mi] = *(const s8v*)&As[cur][ks * 4 + lq][mo + mi * 16 + lrow][0];
#pragma unroll
                for (int ni = 0; ni < 4; ++ni)
                    bfr[ks][ni] = *(const s8v*)&Bs[cur][ks * 4 + lq][no + ni * 16 + lrow][0];
            }
#pragma unroll
            for (int ks = 0; ks < 2; ++ks)
#pragma unroll
                for (int mi = 0; mi < 4; ++mi)
#pragma unroll
                    for (int ni = 0; ni < 4; ++ni)
                        acc[mi][ni] = __builtin_amdgcn_mfma_f32_16x16x32_bf16(af[ks][mi], bfr[ks][ni], acc[mi][ni], 0, 0, 0);
        }
    } else {
        const int NK = (ED / KSPLIT) / BK;   // 32
        float4 L0, L1, L2, L3;
        glds16(a0, &As[0][w][0][0]);
        glds16(a1, &As[0][w][64][0]);
        L0 = *(const float4*)(bp);     L1 = *(const float4*)(bp + 4);
        L2 = *(const float4*)(bp + 8); L3 = *(const float4*)(bp + 12);
        {
            uint4 p0 = { pkbf2(L0.x, L0.y), pkbf2(L0.z, L0.w), pkbf2(L1.x, L1.y), pkbf2(L1.z, L1.w) };
            uint4 p1 = { pkbf2(L2.x, L2.y), pkbf2(L2.z, L2.w), pkbf2(L3.x, L3.y), pkbf2(L3.z, L3.w) };
            *(uint4*)&Bs[0][2 * bq][br][0] = p0;
            *(uint4*)&Bs[0][2 * bq + 1][br][0] = p1;
        }
        L0 = *(const float4*)(bp + BK);     L1 = *(const float4*)(bp + BK + 4);
        L2 = *(const float4*)(bp + BK + 8); L3 = *(const float4*)(bp + BK + 12);
        for (int kk = 0; kk < NK; ++kk) {
            int cur = kk & 1, nxt = cur ^ 1;
            __syncthreads();
            if (kk + 1 < NK) {
                int k0 = (kk + 1) * BK;
                glds16(a0 + k0, &As[nxt][w][0][0]);
                glds16(a1 + k0, &As[nxt][w][64][0]);
                uint4 p0 = { pkbf2(L0.x, L0.y), pkbf2(L0.z, L0.w), pkbf2(L1.x, L1.y), pkbf2(L1.z, L1.w) };
                uint4 p1 = { pkbf2(L2.x, L2.y), pkbf2(L2.z, L2.w), pkbf2(L3.x, L3.y), pkbf2(L3.z, L3.w) };
                *(uint4*)&Bs[nxt][2 * bq][br][0] = p0;
                *(uint4*)&Bs[nxt][2 * bq + 1][br][0] = p1;
                if (kk + 2 < NK) {
                    const float* bpp = bp + (kk + 2) * BK;
                    L0 = *(const float4*)(bpp);     L1 = *(const float4*)(bpp + 4);
                    L2 = *(const float4*)(bpp + 8); L3 = *(const float4*)(bpp + 12);
                }
            }
            s8v af[4], bfr[4];
#pragma unroll
            for (int mi = 0; mi < 4; ++mi) af[mi] = *(const s8v*)&As[cur][lq][mo + mi * 16 + lrow][0];
#pragma unroll
            for (int ni = 0; ni < 4; ++ni) bfr[ni] = *(const s8v*)&Bs[cur][lq][no + ni * 16 + lrow][0];
#pragma unroll
            for (int mi = 0; mi < 4; ++mi)
#pragma unroll
                for (int ni = 0; ni < 4; ++ni)
                    acc[mi][ni] = __builtin_amdgcn_mfma_f32_16x16x32_bf16(af[mi], bfr[ni], acc[mi][ni], 0, 0, 0);
        }
    }

    short* eop = eo + (size_t)ksp * NSLOT * DIM;
#pragma unroll
    for (int mi = 0; mi < 4; ++mi) {
#pragma unroll
        for (int ni = 0; ni < 4; ++ni) {
            int ln = n0 + no + ni * 16 + lrow;
#pragma unroll
            for (int r = 0; r < 4; ++r) {
                int row = m0 + mo + mi * 16 + lq * 4 + r;
                if (row < cnt) {
                    eop[(size_t)(off + row) * DIM + ln] = f2bf(acc[mi][ni][r]);
                }
            }
        }
    }
}

// ---------------- combine ----------------
__global__ __launch_bounds__(256) void combine_kernel(
    const short* __restrict__ eo, const int* __restrict__ slot_of,
    const float* __restrict__ top2w, float* __restrict__ out) {
    int idx = blockIdx.x * 256 + threadIdx.x;
    int t = idx >> 7;
    int c = idx & 127;
    int s0 = slot_of[2 * t], s1 = slot_of[2 * t + 1];
    float w0 = top2w[2 * t], w1 = top2w[2 * t + 1];
    const short* e0 = eo;
    const short* e1 = eo + (size_t)NSLOT * DIM;
    s8v a0 = *(const s8v*)(e0 + (size_t)s0 * DIM + c * 8);
    s8v a1 = *(const s8v*)(e1 + (size_t)s0 * DIM + c * 8);
    s8v b0 = *(const s8v*)(e0 + (size_t)s1 * DIM + c * 8);
    s8v b1 = *(const s8v*)(e1 + (size_t)s1 * DIM + c * 8);
    float4 o[2];
#pragma unroll
    for (int j = 0; j < 8; ++j) {
        float v = w0 * (bf2f(a0[j]) + bf2f(a1[j])) + w1 * (bf2f(b0[j]) + bf2f(b1[j]));
        ((float*)o)[j] = v;
    }
    float4* op = (float4*)(out + (size_t)t * DIM + c * 8);
    op[0] = o[0];
    op[1] = o[1];
}

extern "C" void kernel_launch(void* const* d_in, const int* in_sizes, int n_in,
                              void* d_out, int out_size, void* d_ws, size_t ws_size,
                              hipStream_t stream) {
    const float* x    = (const float*)d_in[0];
    const float* gw   = (const float*)d_in[1];
    const float* bias = (const float*)d_in[2];
    const float* w1   = (const float*)d_in[3];
    const float* w2   = (const float*)d_in[4];
    float* out = (float*)d_out;

    char* ws = (char*)d_ws;
    short* xb = (short*)ws;                           // 4 MiB  [T][DIM] bf16
    short* h  = (short*)(ws + (4ull << 20));          // 16 MiB [NSLOT][ED] bf16
    short* eo = (short*)(ws + (20ull << 20));         // 16 MiB [2][NSLOT][DIM] bf16
    char* meta = ws + (36ull << 20);
    int*   counts   = (int*)(meta);                   // [8]
    int*   offsets  = (int*)(meta + 64);              // [8]
    int*   tok_list = (int*)(meta + 128);             // [NSLOT]
    int*   slot_of  = (int*)(meta + 128 + 4 * NSLOT); // [T*2]
    int*   top2i    = (int*)(meta + 128 + 8 * NSLOT); // [T*2]
    float* top2w    = (float*)(meta + 128 + 8 * NSLOT + 8 * T);
    int*   wl       = (int*)(meta + 128 + 8 * NSLOT + 16 * T);   // [MAXWL]
    int*   nwl      = (int*)(meta + 128 + 8 * NSLOT + 16 * T + 4 * MAXWL);
    short* wb       = (short*)(ws + (37ull << 20));   // 32 MiB bf16 weight buffer (shared w1/w2)

    // need 37 MiB + 32 MiB for the bf16-weight path
    bool bf = ws_size >= (70ull << 20);

    hipMemsetAsync(counts, 0, 32, stream);

    if (bf) {
        convert_kernel<<<2048, 256, 0, stream>>>(w1, wb, NE * ED * DIM / 8);
    }
    router_kernel<<<T / 4, 256, 0, stream>>>(x, gw, bias, xb, counts, top2i, top2w);
    plan_kernel<<<1, 256, 0, stream>>>(counts, top2i, offsets, tok_list, slot_of, wl, nwl);
    if (bf) {
        ffn1_kernel<1><<<dim3(ED / BN, MAXWL), 256, 0, stream>>>(xb, w1, wb, counts, offsets, tok_list, wl, nwl, h);
        convert_kernel<<<2048, 256, 0, stream>>>(w2, wb, NE * DIM * ED / 8);
        ffn2_kernel<1><<<dim3(DIM / BN, MAXWL, KSPLIT), 256, 0, stream>>>(h, w2, wb, counts, offsets, wl, nwl, eo);
    } else {
        ffn1_kernel<0><<<dim3(ED / BN, MAXWL), 256, 0, stream>>>(xb, w1, nullptr, counts, offsets, tok_list, wl, nwl, h);
        ffn2_kernel<0><<<dim3(DIM / BN, MAXWL, KSPLIT), 256, 0, stream>>>(h, w2, nullptr, counts, offsets, wl, nwl, eo);
    }
    combine_kernel<<<T * DIM / 8 / 256, 256, 0, stream>>>(eo, slot_of, top2w, out);
}

// Round 4
// 351.672 us; speedup vs baseline: 1.1005x; 1.0838x over previous
//
#include <hip/hip_runtime.h>

#define T 2048
#define DIM 1024
#define NE 8
#define ED 2048
#define NSLOT (T * 2)
#define KSPLIT 2

#define BM 128
#define BN 64
#define BK 32
#define MAXWL 40

typedef __attribute__((ext_vector_type(8))) short s8v;   // 8 bf16 = 4 VGPRs
typedef __attribute__((ext_vector_type(4))) float f32x4; // MFMA C/D

__device__ __forceinline__ short f2bf(float f) {
    union { float f; unsigned u; } v;
    v.f = f;
    unsigned r = 0x7FFFu + ((v.u >> 16) & 1u);  // round-to-nearest-even
    v.u += r;
    return (short)(v.u >> 16);
}

__device__ __forceinline__ float bf2f(short s) {
    union { unsigned u; float f; } v;
    v.u = ((unsigned)(unsigned short)s) << 16;
    return v.f;
}

// pack two fp32 -> two bf16 (round-half-up) in 3 VALU: add 0x8000, perm high halves
__device__ __forceinline__ unsigned pkbf2(float lo, float hi) {
    union { float f; unsigned u; } a, b;
    a.f = lo; b.f = hi;
    return __builtin_amdgcn_perm(b.u + 0x8000u, a.u + 0x8000u, 0x07060302u);
}

// async global->LDS, 16B per lane; lds dst wave-uniform base, lane i -> base+16i
__device__ __forceinline__ void glds16(const void* g, void* l) {
    __builtin_amdgcn_global_load_lds(
        (const __attribute__((address_space(1))) void*)g,
        (__attribute__((address_space(3))) void*)l, 16, 0, 0);
}

// ---------------- weight convert: fp32 -> bf16, layout-preserving ----------------
__global__ __launch_bounds__(256) void convert_kernel(const float* __restrict__ src,
                                                      short* __restrict__ dst, int n8) {
    int stride = gridDim.x * 256;
    for (int i = blockIdx.x * 256 + threadIdx.x; i < n8; i += stride) {
        float4 a = ((const float4*)src)[2 * i];
        float4 b = ((const float4*)src)[2 * i + 1];
        uint4 o = { pkbf2(a.x, a.y), pkbf2(a.z, a.w), pkbf2(b.x, b.y), pkbf2(b.z, b.w) };
        ((uint4*)dst)[i] = o;
    }
}

// ---------------- router: 1 wave per token (also emits xb = bf16(x)) ----------------
__global__ void router_kernel(const float* __restrict__ x,
                              const float* __restrict__ gw,
                              const float* __restrict__ bias,
                              short* __restrict__ xb,
                              int* __restrict__ counts,
                              int* __restrict__ top2i,
                              float* __restrict__ top2w) {
    int wid = threadIdx.x >> 6;
    int lane = threadIdx.x & 63;
    int t = blockIdx.x * 4 + wid;

    const float* xr = x + (size_t)t * DIM + lane * 16;
    float4 xv[4];
#pragma unroll
    for (int j = 0; j < 4; ++j) xv[j] = *(const float4*)(xr + j * 4);

    s8v o0, o1;
#pragma unroll
    for (int j = 0; j < 2; ++j) {
        o0[j * 4 + 0] = f2bf(xv[j].x); o0[j * 4 + 1] = f2bf(xv[j].y);
        o0[j * 4 + 2] = f2bf(xv[j].z); o0[j * 4 + 3] = f2bf(xv[j].w);
        o1[j * 4 + 0] = f2bf(xv[j + 2].x); o1[j * 4 + 1] = f2bf(xv[j + 2].y);
        o1[j * 4 + 2] = f2bf(xv[j + 2].z); o1[j * 4 + 3] = f2bf(xv[j + 2].w);
    }
    *(s8v*)(xb + (size_t)t * DIM + lane * 16) = o0;
    *(s8v*)(xb + (size_t)t * DIM + lane * 16 + 8) = o1;

    float sc[NE];
#pragma unroll
    for (int e = 0; e < NE; ++e) {
        const float* gr = gw + e * DIM + lane * 16;
        float p = 0.f;
#pragma unroll
        for (int j = 0; j < 4; ++j) {
            float4 g = *(const float4*)(gr + j * 4);
            p += xv[j].x * g.x + xv[j].y * g.y + xv[j].z * g.z + xv[j].w * g.w;
        }
#pragma unroll
        for (int off = 32; off; off >>= 1) p += __shfl_xor(p, off, 64);
        sc[e] = 1.f / (1.f + __expf(-(p + bias[e])));
    }
    int b0 = 0; float s0 = sc[0];
#pragma unroll
    for (int e = 1; e < NE; ++e) if (sc[e] > s0) { s0 = sc[e]; b0 = e; }
    int b1 = -1; float s1 = -1e30f;
#pragma unroll
    for (int e = 0; e < NE; ++e) if (e != b0 && sc[e] > s1) { s1 = sc[e]; b1 = e; }
    float inv = 1.f / (s0 + s1 + 1e-6f);
    if (lane == 0) {
        top2i[t * 2 + 0] = b0; top2i[t * 2 + 1] = b1;
        top2w[t * 2 + 0] = s0 * inv; top2w[t * 2 + 1] = s1 * inv;
        atomicAdd(&counts[b0], 1);
        atomicAdd(&counts[b1], 1);
    }
}

// ---------------- plan: prefix + worklist + scatter ----------------
__global__ __launch_bounds__(256) void plan_kernel(
    const int* __restrict__ counts, const int* __restrict__ top2i,
    int* __restrict__ offsets, int* __restrict__ tok_list, int* __restrict__ slot_of,
    int* __restrict__ wl, int* __restrict__ nwl) {
    __shared__ int soff[NE];
    __shared__ int srun[NE];
    if (threadIdx.x == 0) {
        int a = 0;
        for (int e = 0; e < NE; ++e) { soff[e] = a; offsets[e] = a; a += counts[e]; srun[e] = 0; }
        int n = 0;
        for (int e = 0; e < NE; ++e) {
            int mt = (counts[e] + BM - 1) / BM;
            for (int m = 0; m < mt; ++m) wl[n++] = (e << 16) | m;
        }
        *nwl = n;
    }
    __syncthreads();
    for (int t = threadIdx.x; t < T; t += 256) {
#pragma unroll
        for (int k = 0; k < 2; ++k) {
            int e = top2i[t * 2 + k];
            int pos = atomicAdd(&srun[e], 1);
            int slot = soff[e] + pos;
            tok_list[slot] = t;
            slot_of[t * 2 + k] = slot;
        }
    }
}

// ---------------- grouped GEMM1: h = silu(x @ w1^T) ----------------
// BM=128 x BN=64, BK=32, round-1 single-barrier dbuf pipeline (best measured).
// Wave w: rows mo=w*32, all 64 cols. acc[2][4]. 24 KiB LDS -> 6 blocks/CU cap.
// BF=1: B via glds16 from bf16 weights. BF=0: fp32 reg-pack fallback.
template <int BF>
__global__ __launch_bounds__(256) void ffn1_kernel(
    const short* __restrict__ xb, const float* __restrict__ w1,
    const short* __restrict__ wb,
    const int* __restrict__ counts, const int* __restrict__ offsets,
    const int* __restrict__ tok_list, const int* __restrict__ wl,
    const int* __restrict__ nwl, short* __restrict__ h) {
    int my = blockIdx.y;
    if (my >= *nwl) return;
    int e = wl[my] >> 16;
    int m0 = (wl[my] & 0xffff) * BM;
    int cnt = counts[e];
    int off = offsets[e];
    int n0 = blockIdx.x * BN;

    __shared__ __align__(16) short As[2][4][BM][8];   // 16 KiB
    __shared__ __align__(16) short Bs[2][4][BN][8];   // 8 KiB

    int tid = threadIdx.x;
    int lane = tid & 63, w = tid >> 6;
    int mo = w * 32;
    int lrow = lane & 15, lq = lane >> 4;

    f32x4 acc[2][4];
#pragma unroll
    for (int mi = 0; mi < 2; ++mi)
#pragma unroll
        for (int ni = 0; ni < 4; ++ni) acc[mi][ni] = (f32x4){0.f, 0.f, 0.f, 0.f};

    int ra0 = m0 + lane;      if (ra0 > cnt - 1) ra0 = cnt - 1;
    int ra1 = m0 + 64 + lane; if (ra1 > cnt - 1) ra1 = cnt - 1;
    const short* a0 = xb + (size_t)tok_list[off + ra0] * DIM + w * 8;
    const short* a1 = xb + (size_t)tok_list[off + ra1] * DIM + w * 8;

    // BF: wave w stages B k-quad w for all 64 rows (1 glds16)
    const short* b0 = wb + ((size_t)e * ED + n0 + lane) * DIM + w * 8;
    // fp32 fallback: thread (br=tid>>2, bq=tid&3) loads 8 fp32 of row n0+br, k-oct bq
    int br = tid >> 2, bq = tid & 3;
    const float* bp = w1 + ((size_t)e * ED + n0 + br) * DIM + bq * 8;

    const int NK = DIM / BK;   // 32

    if constexpr (BF) {
        auto stage = [&](int s, int b) {
            int k0 = s * BK;
            glds16(a0 + k0, &As[b][w][0][0]);
            glds16(a1 + k0, &As[b][w][64][0]);
            glds16(b0 + k0, &Bs[b][w][0][0]);
        };
        stage(0, 0);
        for (int kk = 0; kk < NK; ++kk) {
            int cur = kk & 1, nxt = cur ^ 1;
            __syncthreads();   // buf[cur] landed everywhere
            if (kk + 1 < NK) stage(kk + 1, nxt);
            s8v af[2], bfr[4];
#pragma unroll
            for (int mi = 0; mi < 2; ++mi) af[mi] = *(const s8v*)&As[cur][lq][mo + mi * 16 + lrow][0];
#pragma unroll
            for (int ni = 0; ni < 4; ++ni) bfr[ni] = *(const s8v*)&Bs[cur][lq][ni * 16 + lrow][0];
#pragma unroll
            for (int mi = 0; mi < 2; ++mi)
#pragma unroll
                for (int ni = 0; ni < 4; ++ni)
                    acc[mi][ni] = __builtin_amdgcn_mfma_f32_16x16x32_bf16(af[mi], bfr[ni], acc[mi][ni], 0, 0, 0);
        }
    } else {
        float4 L0, L1;
        glds16(a0, &As[0][w][0][0]);
        glds16(a1, &As[0][w][64][0]);
        L0 = *(const float4*)(bp); L1 = *(const float4*)(bp + 4);
        {
            uint4 p0 = { pkbf2(L0.x, L0.y), pkbf2(L0.z, L0.w), pkbf2(L1.x, L1.y), pkbf2(L1.z, L1.w) };
            *(uint4*)&Bs[0][bq][br][0] = p0;
        }
        L0 = *(const float4*)(bp + BK); L1 = *(const float4*)(bp + BK + 4);
        for (int kk = 0; kk < NK; ++kk) {
            int cur = kk & 1, nxt = cur ^ 1;
            __syncthreads();
            if (kk + 1 < NK) {
                int k0 = (kk + 1) * BK;
                glds16(a0 + k0, &As[nxt][w][0][0]);
                glds16(a1 + k0, &As[nxt][w][64][0]);
                uint4 p0 = { pkbf2(L0.x, L0.y), pkbf2(L0.z, L0.w), pkbf2(L1.x, L1.y), pkbf2(L1.z, L1.w) };
                *(uint4*)&Bs[nxt][bq][br][0] = p0;
                if (kk + 2 < NK) {
                    const float* bpp = bp + (kk + 2) * BK;
                    L0 = *(const float4*)(bpp); L1 = *(const float4*)(bpp + 4);
                }
            }
            s8v af[2], bfr[4];
#pragma unroll
            for (int mi = 0; mi < 2; ++mi) af[mi] = *(const s8v*)&As[cur][lq][mo + mi * 16 + lrow][0];
#pragma unroll
            for (int ni = 0; ni < 4; ++ni) bfr[ni] = *(const s8v*)&Bs[cur][lq][ni * 16 + lrow][0];
#pragma unroll
            for (int mi = 0; mi < 2; ++mi)
#pragma unroll
                for (int ni = 0; ni < 4; ++ni)
                    acc[mi][ni] = __builtin_amdgcn_mfma_f32_16x16x32_bf16(af[mi], bfr[ni], acc[mi][ni], 0, 0, 0);
        }
    }

#pragma unroll
    for (int mi = 0; mi < 2; ++mi) {
#pragma unroll
        for (int ni = 0; ni < 4; ++ni) {
            int ln = n0 + ni * 16 + lrow;
#pragma unroll
            for (int r = 0; r < 4; ++r) {
                int row = m0 + mo + mi * 16 + lq * 4 + r;
                if (row < cnt) {
                    float v = acc[mi][ni][r];
                    v = v / (1.f + __expf(-v));  // silu
                    h[(size_t)(off + row) * ED + ln] = f2bf(v);
                }
            }
        }
    }
}

// ---------------- grouped GEMM2 (K-split): eo[ks][slot] = h @ w2^T[kchunk] ----------------
template <int BF>
__global__ __launch_bounds__(256) void ffn2_kernel(
    const short* __restrict__ h, const float* __restrict__ w2,
    const short* __restrict__ wb,
    const int* __restrict__ counts, const int* __restrict__ offsets,
    const int* __restrict__ wl, const int* __restrict__ nwl,
    short* __restrict__ eo) {
    int my = blockIdx.y;
    if (my >= *nwl) return;
    int e = wl[my] >> 16;
    int m0 = (wl[my] & 0xffff) * BM;
    int ksp = blockIdx.z;
    int cnt = counts[e];
    int off = offsets[e];
    int n0 = blockIdx.x * BN;
    const int kbase = ksp * (ED / KSPLIT);

    __shared__ __align__(16) short As[2][4][BM][8];
    __shared__ __align__(16) short Bs[2][4][BN][8];

    int tid = threadIdx.x;
    int lane = tid & 63, w = tid >> 6;
    int mo = w * 32;
    int lrow = lane & 15, lq = lane >> 4;

    f32x4 acc[2][4];
#pragma unroll
    for (int mi = 0; mi < 2; ++mi)
#pragma unroll
        for (int ni = 0; ni < 4; ++ni) acc[mi][ni] = (f32x4){0.f, 0.f, 0.f, 0.f};

    int ra0 = m0 + lane;      if (ra0 > cnt - 1) ra0 = cnt - 1;
    int ra1 = m0 + 64 + lane; if (ra1 > cnt - 1) ra1 = cnt - 1;
    const short* a0 = h + (size_t)(off + ra0) * ED + kbase + w * 8;
    const short* a1 = h + (size_t)(off + ra1) * ED + kbase + w * 8;

    const short* b0 = wb + ((size_t)e * DIM + n0 + lane) * ED + kbase + w * 8;
    int br = tid >> 2, bq = tid & 3;
    const float* bp = w2 + ((size_t)e * DIM + n0 + br) * ED + kbase + bq * 8;

    const int NK = (ED / KSPLIT) / BK;   // 32

    if constexpr (BF) {
        auto stage = [&](int s, int b) {
            int k0 = s * BK;
            glds16(a0 + k0, &As[b][w][0][0]);
            glds16(a1 + k0, &As[b][w][64][0]);
            glds16(b0 + k0, &Bs[b][w][0][0]);
        };
        stage(0, 0);
        for (int kk = 0; kk < NK; ++kk) {
            int cur = kk & 1, nxt = cur ^ 1;
            __syncthreads();
            if (kk + 1 < NK) stage(kk + 1, nxt);
            s8v af[2], bfr[4];
#pragma unroll
            for (int mi = 0; mi < 2; ++mi) af[mi] = *(const s8v*)&As[cur][lq][mo + mi * 16 + lrow][0];
#pragma unroll
            for (int ni = 0; ni < 4; ++ni) bfr[ni] = *(const s8v*)&Bs[cur][lq][ni * 16 + lrow][0];
#pragma unroll
            for (int mi = 0; mi < 2; ++mi)
#pragma unroll
                for (int ni = 0; ni < 4; ++ni)
                    acc[mi][ni] = __builtin_amdgcn_mfma_f32_16x16x32_bf16(af[mi], bfr[ni], acc[mi][ni], 0, 0, 0);
        }
    } else {
        float4 L0, L1;
        glds16(a0, &As[0][w][0][0]);
        glds16(a1, &As[0][w][64][0]);
        L0 = *(const float4*)(bp); L1 = *(const float4*)(bp + 4);
        {
            uint4 p0 = { pkbf2(L0.x, L0.y), pkbf2(L0.z, L0.w), pkbf2(L1.x, L1.y), pkbf2(L1.z, L1.w) };
            *(uint4*)&Bs[0][bq][br][0] = p0;
        }
        L0 = *(const float4*)(bp + BK); L1 = *(const float4*)(bp + BK + 4);
        for (int kk = 0; kk < NK; ++kk) {
            int cur = kk & 1, nxt = cur ^ 1;
            __syncthreads();
            if (kk + 1 < NK) {
                int k0 = (kk + 1) * BK;
                glds16(a0 + k0, &As[nxt][w][0][0]);
                glds16(a1 + k0, &As[nxt][w][64][0]);
                uint4 p0 = { pkbf2(L0.x, L0.y), pkbf2(L0.z, L0.w), pkbf2(L1.x, L1.y), pkbf2(L1.z, L1.w) };
                *(uint4*)&Bs[nxt][bq][br][0] = p0;
                if (kk + 2 < NK) {
                    const float* bpp = bp + (kk + 2) * BK;
                    L0 = *(const float4*)(bpp); L1 = *(const float4*)(bpp + 4);
                }
            }
            s8v af[2], bfr[4];
#pragma unroll
            for (int mi = 0; mi < 2; ++mi) af[mi] = *(const s8v*)&As[cur][lq][mo + mi * 16 + lrow][0];
#pragma unroll
            for (int ni = 0; ni < 4; ++ni) bfr[ni] = *(const s8v*)&Bs[cur][lq][ni * 16 + lrow][0];
#pragma unroll
            for (int mi = 0; mi < 2; ++mi)
#pragma unroll
                for (int ni = 0; ni < 4; ++ni)
                    acc[mi][ni] = __builtin_amdgcn_mfma_f32_16x16x32_bf16(af[mi], bfr[ni], acc[mi][ni], 0, 0, 0);
        }
    }

    short* eop = eo + (size_t)ksp * NSLOT * DIM;
#pragma unroll
    for (int mi = 0; mi < 2; ++mi) {
#pragma unroll
        for (int ni = 0; ni < 4; ++ni) {
            int ln = n0 + ni * 16 + lrow;
#pragma unroll
            for (int r = 0; r < 4; ++r) {
                int row = m0 + mo + mi * 16 + lq * 4 + r;
                if (row < cnt) {
                    eop[(size_t)(off + row) * DIM + ln] = f2bf(acc[mi][ni][r]);
                }
            }
        }
    }
}

// ---------------- combine ----------------
__global__ __launch_bounds__(256) void combine_kernel(
    const short* __restrict__ eo, const int* __restrict__ slot_of,
    const float* __restrict__ top2w, float* __restrict__ out) {
    int idx = blockIdx.x * 256 + threadIdx.x;
    int t = idx >> 7;
    int c = idx & 127;
    int s0 = slot_of[2 * t], s1 = slot_of[2 * t + 1];
    float w0 = top2w[2 * t], w1 = top2w[2 * t + 1];
    const short* e0 = eo;
    const short* e1 = eo + (size_t)NSLOT * DIM;
    s8v a0 = *(const s8v*)(e0 + (size_t)s0 * DIM + c * 8);
    s8v a1 = *(const s8v*)(e1 + (size_t)s0 * DIM + c * 8);
    s8v b0 = *(const s8v*)(e0 + (size_t)s1 * DIM + c * 8);
    s8v b1 = *(const s8v*)(e1 + (size_t)s1 * DIM + c * 8);
    float4 o[2];
#pragma unroll
    for (int j = 0; j < 8; ++j) {
        float v = w0 * (bf2f(a0[j]) + bf2f(a1[j])) + w1 * (bf2f(b0[j]) + bf2f(b1[j]));
        ((float*)o)[j] = v;
    }
    float4* op = (float4*)(out + (size_t)t * DIM + c * 8);
    op[0] = o[0];
    op[1] = o[1];
}

extern "C" void kernel_launch(void* const* d_in, const int* in_sizes, int n_in,
                              void* d_out, int out_size, void* d_ws, size_t ws_size,
                              hipStream_t stream) {
    const float* x    = (const float*)d_in[0];
    const float* gw   = (const float*)d_in[1];
    const float* bias = (const float*)d_in[2];
    const float* w1   = (const float*)d_in[3];
    const float* w2   = (const float*)d_in[4];
    float* out = (float*)d_out;

    char* ws = (char*)d_ws;
    short* xb = (short*)ws;                           // 4 MiB  [T][DIM] bf16
    short* h  = (short*)(ws + (4ull << 20));          // 16 MiB [NSLOT][ED] bf16
    short* eo = (short*)(ws + (20ull << 20));         // 16 MiB [2][NSLOT][DIM] bf16
    char* meta = ws + (36ull << 20);
    int*   counts   = (int*)(meta);                   // [8]
    int*   offsets  = (int*)(meta + 64);              // [8]
    int*   tok_list = (int*)(meta + 128);             // [NSLOT]
    int*   slot_of  = (int*)(meta + 128 + 4 * NSLOT); // [T*2]
    int*   top2i    = (int*)(meta + 128 + 8 * NSLOT); // [T*2]
    float* top2w    = (float*)(meta + 128 + 8 * NSLOT + 8 * T);
    int*   wl       = (int*)(meta + 128 + 8 * NSLOT + 16 * T);   // [MAXWL]
    int*   nwl      = (int*)(meta + 128 + 8 * NSLOT + 16 * T + 4 * MAXWL);
    short* wb       = (short*)(ws + (37ull << 20));   // 32 MiB bf16 weight buffer (shared w1/w2)

    // need 37 MiB + 32 MiB for the bf16-weight path
    bool bf = ws_size >= (70ull << 20);

    hipMemsetAsync(counts, 0, 32, stream);

    if (bf) {
        convert_kernel<<<2048, 256, 0, stream>>>(w1, wb, NE * ED * DIM / 8);
    }
    router_kernel<<<T / 4, 256, 0, stream>>>(x, gw, bias, xb, counts, top2i, top2w);
    plan_kernel<<<1, 256, 0, stream>>>(counts, top2i, offsets, tok_list, slot_of, wl, nwl);
    if (bf) {
        ffn1_kernel<1><<<dim3(ED / BN, MAXWL), 256, 0, stream>>>(xb, w1, wb, counts, offsets, tok_list, wl, nwl, h);
        convert_kernel<<<2048, 256, 0, stream>>>(w2, wb, NE * DIM * ED / 8);
        ffn2_kernel<1><<<dim3(DIM / BN, MAXWL, KSPLIT), 256, 0, stream>>>(h, w2, wb, counts, offsets, wl, nwl, eo);
    } else {
        ffn1_kernel<0><<<dim3(ED / BN, MAXWL), 256, 0, stream>>>(xb, w1, nullptr, counts, offsets, tok_list, wl, nwl, h);
        ffn2_kernel<0><<<dim3(DIM / BN, MAXWL, KSPLIT), 256, 0, stream>>>(h, w2, nullptr, counts, offsets, wl, nwl, eo);
    }
    combine_kernel<<<T * DIM / 8 / 256, 256, 0, stream>>>(eo, slot_of, top2w, out);
}

// Round 5
// 347.353 us; speedup vs baseline: 1.1142x; 1.0124x over previous
//
#include <hip/hip_runtime.h>

#define T 2048
#define DIM 1024
#define NE 8
#define ED 2048
#define NSLOT (T * 2)
#define KSPLIT 2

#define BM 128
#define BN 64
#define BK 32

typedef __attribute__((ext_vector_type(8))) short s8v;   // 8 bf16 = 4 VGPRs
typedef __attribute__((ext_vector_type(4))) float f32x4; // MFMA C/D

__device__ __forceinline__ short f2bf(float f) {
    union { float f; unsigned u; } v;
    v.f = f;
    unsigned r = 0x7FFFu + ((v.u >> 16) & 1u);  // round-to-nearest-even
    v.u += r;
    return (short)(v.u >> 16);
}

__device__ __forceinline__ float bf2f(short s) {
    union { unsigned u; float f; } v;
    v.u = ((unsigned)(unsigned short)s) << 16;
    return v.f;
}

// pack two fp32 -> two bf16 (round-half-up) in 3 VALU: add 0x8000, perm high halves
__device__ __forceinline__ unsigned pkbf2(float lo, float hi) {
    union { float f; unsigned u; } a, b;
    a.f = lo; b.f = hi;
    return __builtin_amdgcn_perm(b.u + 0x8000u, a.u + 0x8000u, 0x07060302u);
}

// async global->LDS, 16B per lane; lds dst wave-uniform base, lane i -> base+16i
__device__ __forceinline__ void glds16(const void* g, void* l) {
    __builtin_amdgcn_global_load_lds(
        (const __attribute__((address_space(1))) void*)g,
        (__attribute__((address_space(3))) void*)l, 16, 0, 0);
}

// ---------------- weight convert: fp32 -> bf16, layout-preserving ----------------
__global__ __launch_bounds__(256) void convert_kernel(const float* __restrict__ src,
                                                      short* __restrict__ dst, int n8) {
    int stride = gridDim.x * 256;
    for (int i = blockIdx.x * 256 + threadIdx.x; i < n8; i += stride) {
        float4 a = ((const float4*)src)[2 * i];
        float4 b = ((const float4*)src)[2 * i + 1];
        uint4 o = { pkbf2(a.x, a.y), pkbf2(a.z, a.w), pkbf2(b.x, b.y), pkbf2(b.z, b.w) };
        ((uint4*)dst)[i] = o;
    }
}

// ---------------- router: 1 wave per token (also emits xb = bf16(x)) ----------------
__global__ void router_kernel(const float* __restrict__ x,
                              const float* __restrict__ gw,
                              const float* __restrict__ bias,
                              short* __restrict__ xb,
                              int* __restrict__ counts,
                              int* __restrict__ top2i,
                              float* __restrict__ top2w) {
    int wid = threadIdx.x >> 6;
    int lane = threadIdx.x & 63;
    int t = blockIdx.x * 4 + wid;

    const float* xr = x + (size_t)t * DIM + lane * 16;
    float4 xv[4];
#pragma unroll
    for (int j = 0; j < 4; ++j) xv[j] = *(const float4*)(xr + j * 4);

    s8v o0, o1;
#pragma unroll
    for (int j = 0; j < 2; ++j) {
        o0[j * 4 + 0] = f2bf(xv[j].x); o0[j * 4 + 1] = f2bf(xv[j].y);
        o0[j * 4 + 2] = f2bf(xv[j].z); o0[j * 4 + 3] = f2bf(xv[j].w);
        o1[j * 4 + 0] = f2bf(xv[j + 2].x); o1[j * 4 + 1] = f2bf(xv[j + 2].y);
        o1[j * 4 + 2] = f2bf(xv[j + 2].z); o1[j * 4 + 3] = f2bf(xv[j + 2].w);
    }
    *(s8v*)(xb + (size_t)t * DIM + lane * 16) = o0;
    *(s8v*)(xb + (size_t)t * DIM + lane * 16 + 8) = o1;

    float sc[NE];
#pragma unroll
    for (int e = 0; e < NE; ++e) {
        const float* gr = gw + e * DIM + lane * 16;
        float p = 0.f;
#pragma unroll
        for (int j = 0; j < 4; ++j) {
            float4 g = *(const float4*)(gr + j * 4);
            p += xv[j].x * g.x + xv[j].y * g.y + xv[j].z * g.z + xv[j].w * g.w;
        }
#pragma unroll
        for (int off = 32; off; off >>= 1) p += __shfl_xor(p, off, 64);
        sc[e] = 1.f / (1.f + __expf(-(p + bias[e])));
    }
    int b0 = 0; float s0 = sc[0];
#pragma unroll
    for (int e = 1; e < NE; ++e) if (sc[e] > s0) { s0 = sc[e]; b0 = e; }
    int b1 = -1; float s1 = -1e30f;
#pragma unroll
    for (int e = 0; e < NE; ++e) if (e != b0 && sc[e] > s1) { s1 = sc[e]; b1 = e; }
    float inv = 1.f / (s0 + s1 + 1e-6f);
    if (lane == 0) {
        top2i[t * 2 + 0] = b0; top2i[t * 2 + 1] = b1;
        top2w[t * 2 + 0] = s0 * inv; top2w[t * 2 + 1] = s1 * inv;
        atomicAdd(&counts[b0], 1);
        atomicAdd(&counts[b1], 1);
    }
}

// ---------------- plan: prefix + scatter ----------------
__global__ __launch_bounds__(256) void plan_kernel(
    const int* __restrict__ counts, const int* __restrict__ top2i,
    int* __restrict__ offsets, int* __restrict__ tok_list, int* __restrict__ slot_of) {
    __shared__ int soff[NE];
    __shared__ int srun[NE];
    if (threadIdx.x == 0) {
        int a = 0;
        for (int e = 0; e < NE; ++e) { soff[e] = a; offsets[e] = a; a += counts[e]; srun[e] = 0; }
    }
    __syncthreads();
    for (int t = threadIdx.x; t < T; t += 256) {
#pragma unroll
        for (int k = 0; k < 2; ++k) {
            int e = top2i[t * 2 + k];
            int pos = atomicAdd(&srun[e], 1);
            int slot = soff[e] + pos;
            tok_list[slot] = t;
            slot_of[t * 2 + k] = slot;
        }
    }
}

// ---------------- grouped GEMM1: h = silu(x @ w1^T) ----------------
// XCD-affinity 1-D grid: bid&7 = expert (-> XCD via round-robin dispatch),
// bid>>3 = job (m-tile * 32 n-tiles). Each XCD's L2 holds ONE expert's
// w1 slice (4 MiB) + its token rows -> staging hits L2 instead of L3.
// Inner loop: r4's single-barrier dbuf, BM=128 x BN=64, BK=32, 24 KiB LDS.
template <int BF>
__global__ __launch_bounds__(256) void ffn1_kernel(
    const short* __restrict__ xb, const float* __restrict__ w1,
    const short* __restrict__ wb,
    const int* __restrict__ counts, const int* __restrict__ offsets,
    const int* __restrict__ tok_list, short* __restrict__ h) {
    int e = blockIdx.x & 7;
    int j = blockIdx.x >> 3;
    int cnt = counts[e];
    const int NT = ED / BN;   // 32
    int mt = (cnt + BM - 1) / BM;
    if (j >= mt * NT) return;
    int m0 = (j / NT) * BM;
    int n0 = (j % NT) * BN;
    int off = offsets[e];

    __shared__ __align__(16) short As[2][4][BM][8];   // 16 KiB
    __shared__ __align__(16) short Bs[2][4][BN][8];   // 8 KiB

    int tid = threadIdx.x;
    int lane = tid & 63, w = tid >> 6;
    int mo = w * 32;
    int lrow = lane & 15, lq = lane >> 4;

    f32x4 acc[2][4];
#pragma unroll
    for (int mi = 0; mi < 2; ++mi)
#pragma unroll
        for (int ni = 0; ni < 4; ++ni) acc[mi][ni] = (f32x4){0.f, 0.f, 0.f, 0.f};

    int ra0 = m0 + lane;      if (ra0 > cnt - 1) ra0 = cnt - 1;
    int ra1 = m0 + 64 + lane; if (ra1 > cnt - 1) ra1 = cnt - 1;
    const short* a0 = xb + (size_t)tok_list[off + ra0] * DIM + w * 8;
    const short* a1 = xb + (size_t)tok_list[off + ra1] * DIM + w * 8;

    const short* b0 = wb + ((size_t)e * ED + n0 + lane) * DIM + w * 8;
    int br = tid >> 2, bq = tid & 3;
    const float* bp = w1 + ((size_t)e * ED + n0 + br) * DIM + bq * 8;

    const int NK = DIM / BK;   // 32

    if constexpr (BF) {
        auto stage = [&](int s, int b) {
            int k0 = s * BK;
            glds16(a0 + k0, &As[b][w][0][0]);
            glds16(a1 + k0, &As[b][w][64][0]);
            glds16(b0 + k0, &Bs[b][w][0][0]);
        };
        stage(0, 0);
        for (int kk = 0; kk < NK; ++kk) {
            int cur = kk & 1, nxt = cur ^ 1;
            __syncthreads();   // buf[cur] landed everywhere
            if (kk + 1 < NK) stage(kk + 1, nxt);
            s8v af[2], bfr[4];
#pragma unroll
            for (int mi = 0; mi < 2; ++mi) af[mi] = *(const s8v*)&As[cur][lq][mo + mi * 16 + lrow][0];
#pragma unroll
            for (int ni = 0; ni < 4; ++ni) bfr[ni] = *(const s8v*)&Bs[cur][lq][ni * 16 + lrow][0];
#pragma unroll
            for (int mi = 0; mi < 2; ++mi)
#pragma unroll
                for (int ni = 0; ni < 4; ++ni)
                    acc[mi][ni] = __builtin_amdgcn_mfma_f32_16x16x32_bf16(af[mi], bfr[ni], acc[mi][ni], 0, 0, 0);
        }
    } else {
        float4 L0, L1;
        glds16(a0, &As[0][w][0][0]);
        glds16(a1, &As[0][w][64][0]);
        L0 = *(const float4*)(bp); L1 = *(const float4*)(bp + 4);
        {
            uint4 p0 = { pkbf2(L0.x, L0.y), pkbf2(L0.z, L0.w), pkbf2(L1.x, L1.y), pkbf2(L1.z, L1.w) };
            *(uint4*)&Bs[0][bq][br][0] = p0;
        }
        L0 = *(const float4*)(bp + BK); L1 = *(const float4*)(bp + BK + 4);
        for (int kk = 0; kk < NK; ++kk) {
            int cur = kk & 1, nxt = cur ^ 1;
            __syncthreads();
            if (kk + 1 < NK) {
                int k0 = (kk + 1) * BK;
                glds16(a0 + k0, &As[nxt][w][0][0]);
                glds16(a1 + k0, &As[nxt][w][64][0]);
                uint4 p0 = { pkbf2(L0.x, L0.y), pkbf2(L0.z, L0.w), pkbf2(L1.x, L1.y), pkbf2(L1.z, L1.w) };
                *(uint4*)&Bs[nxt][bq][br][0] = p0;
                if (kk + 2 < NK) {
                    const float* bpp = bp + (kk + 2) * BK;
                    L0 = *(const float4*)(bpp); L1 = *(const float4*)(bpp + 4);
                }
            }
            s8v af[2], bfr[4];
#pragma unroll
            for (int mi = 0; mi < 2; ++mi) af[mi] = *(const s8v*)&As[cur][lq][mo + mi * 16 + lrow][0];
#pragma unroll
            for (int ni = 0; ni < 4; ++ni) bfr[ni] = *(const s8v*)&Bs[cur][lq][ni * 16 + lrow][0];
#pragma unroll
            for (int mi = 0; mi < 2; ++mi)
#pragma unroll
                for (int ni = 0; ni < 4; ++ni)
                    acc[mi][ni] = __builtin_amdgcn_mfma_f32_16x16x32_bf16(af[mi], bfr[ni], acc[mi][ni], 0, 0, 0);
        }
    }

#pragma unroll
    for (int mi = 0; mi < 2; ++mi) {
#pragma unroll
        for (int ni = 0; ni < 4; ++ni) {
            int ln = n0 + ni * 16 + lrow;
#pragma unroll
            for (int r = 0; r < 4; ++r) {
                int row = m0 + mo + mi * 16 + lq * 4 + r;
                if (row < cnt) {
                    float v = acc[mi][ni][r];
                    v = v / (1.f + __expf(-v));  // silu
                    h[(size_t)(off + row) * ED + ln] = f2bf(v);
                }
            }
        }
    }
}

// ---------------- grouped GEMM2 (K-split): eo[ks][slot] = h @ w2^T[kchunk] ----------------
template <int BF>
__global__ __launch_bounds__(256) void ffn2_kernel(
    const short* __restrict__ h, const float* __restrict__ w2,
    const short* __restrict__ wb,
    const int* __restrict__ counts, const int* __restrict__ offsets,
    short* __restrict__ eo) {
    int e = blockIdx.x & 7;
    int j = blockIdx.x >> 3;
    int cnt = counts[e];
    const int NT = DIM / BN;   // 16
    int mt = (cnt + BM - 1) / BM;
    if (j >= mt * NT * KSPLIT) return;
    int ksp = j & 1; j >>= 1;
    int m0 = (j / NT) * BM;
    int n0 = (j % NT) * BN;
    int off = offsets[e];
    const int kbase = ksp * (ED / KSPLIT);

    __shared__ __align__(16) short As[2][4][BM][8];
    __shared__ __align__(16) short Bs[2][4][BN][8];

    int tid = threadIdx.x;
    int lane = tid & 63, w = tid >> 6;
    int mo = w * 32;
    int lrow = lane & 15, lq = lane >> 4;

    f32x4 acc[2][4];
#pragma unroll
    for (int mi = 0; mi < 2; ++mi)
#pragma unroll
        for (int ni = 0; ni < 4; ++ni) acc[mi][ni] = (f32x4){0.f, 0.f, 0.f, 0.f};

    int ra0 = m0 + lane;      if (ra0 > cnt - 1) ra0 = cnt - 1;
    int ra1 = m0 + 64 + lane; if (ra1 > cnt - 1) ra1 = cnt - 1;
    const short* a0 = h + (size_t)(off + ra0) * ED + kbase + w * 8;
    const short* a1 = h + (size_t)(off + ra1) * ED + kbase + w * 8;

    const short* b0 = wb + ((size_t)e * DIM + n0 + lane) * ED + kbase + w * 8;
    int br = tid >> 2, bq = tid & 3;
    const float* bp = w2 + ((size_t)e * DIM + n0 + br) * ED + kbase + bq * 8;

    const int NK = (ED / KSPLIT) / BK;   // 32

    if constexpr (BF) {
        auto stage = [&](int s, int b) {
            int k0 = s * BK;
            glds16(a0 + k0, &As[b][w][0][0]);
            glds16(a1 + k0, &As[b][w][64][0]);
            glds16(b0 + k0, &Bs[b][w][0][0]);
        };
        stage(0, 0);
        for (int kk = 0; kk < NK; ++kk) {
            int cur = kk & 1, nxt = cur ^ 1;
            __syncthreads();
            if (kk + 1 < NK) stage(kk + 1, nxt);
            s8v af[2], bfr[4];
#pragma unroll
            for (int mi = 0; mi < 2; ++mi) af[mi] = *(const s8v*)&As[cur][lq][mo + mi * 16 + lrow][0];
#pragma unroll
            for (int ni = 0; ni < 4; ++ni) bfr[ni] = *(const s8v*)&Bs[cur][lq][ni * 16 + lrow][0];
#pragma unroll
            for (int mi = 0; mi < 2; ++mi)
#pragma unroll
                for (int ni = 0; ni < 4; ++ni)
                    acc[mi][ni] = __builtin_amdgcn_mfma_f32_16x16x32_bf16(af[mi], bfr[ni], acc[mi][ni], 0, 0, 0);
        }
    } else {
        float4 L0, L1;
        glds16(a0, &As[0][w][0][0]);
        glds16(a1, &As[0][w][64][0]);
        L0 = *(const float4*)(bp); L1 = *(const float4*)(bp + 4);
        {
            uint4 p0 = { pkbf2(L0.x, L0.y), pkbf2(L0.z, L0.w), pkbf2(L1.x, L1.y), pkbf2(L1.z, L1.w) };
            *(uint4*)&Bs[0][bq][br][0] = p0;
        }
        L0 = *(const float4*)(bp + BK); L1 = *(const float4*)(bp + BK + 4);
        for (int kk = 0; kk < NK; ++kk) {
            int cur = kk & 1, nxt = cur ^ 1;
            __syncthreads();
            if (kk + 1 < NK) {
                int k0 = (kk + 1) * BK;
                glds16(a0 + k0, &As[nxt][w][0][0]);
                glds16(a1 + k0, &As[nxt][w][64][0]);
                uint4 p0 = { pkbf2(L0.x, L0.y), pkbf2(L0.z, L0.w), pkbf2(L1.x, L1.y), pkbf2(L1.z, L1.w) };
                *(uint4*)&Bs[nxt][bq][br][0] = p0;
                if (kk + 2 < NK) {
                    const float* bpp = bp + (kk + 2) * BK;
                    L0 = *(const float4*)(bpp); L1 = *(const float4*)(bpp + 4);
                }
            }
            s8v af[2], bfr[4];
#pragma unroll
            for (int mi = 0; mi < 2; ++mi) af[mi] = *(const s8v*)&As[cur][lq][mo + mi * 16 + lrow][0];
#pragma unroll
            for (int ni = 0; ni < 4; ++ni) bfr[ni] = *(const s8v*)&Bs[cur][lq][ni * 16 + lrow][0];
#pragma unroll
            for (int mi = 0; mi < 2; ++mi)
#pragma unroll
                for (int ni = 0; ni < 4; ++ni)
                    acc[mi][ni] = __builtin_amdgcn_mfma_f32_16x16x32_bf16(af[mi], bfr[ni], acc[mi][ni], 0, 0, 0);
        }
    }

    short* eop = eo + (size_t)ksp * NSLOT * DIM;
#pragma unroll
    for (int mi = 0; mi < 2; ++mi) {
#pragma unroll
        for (int ni = 0; ni < 4; ++ni) {
            int ln = n0 + ni * 16 + lrow;
#pragma unroll
            for (int r = 0; r < 4; ++r) {
                int row = m0 + mo + mi * 16 + lq * 4 + r;
                if (row < cnt) {
                    eop[(size_t)(off + row) * DIM + ln] = f2bf(acc[mi][ni][r]);
                }
            }
        }
    }
}

// ---------------- combine ----------------
__global__ __launch_bounds__(256) void combine_kernel(
    const short* __restrict__ eo, const int* __restrict__ slot_of,
    const float* __restrict__ top2w, float* __restrict__ out) {
    int idx = blockIdx.x * 256 + threadIdx.x;
    int t = idx >> 7;
    int c = idx & 127;
    int s0 = slot_of[2 * t], s1 = slot_of[2 * t + 1];
    float w0 = top2w[2 * t], w1 = top2w[2 * t + 1];
    const short* e0 = eo;
    const short* e1 = eo + (size_t)NSLOT * DIM;
    s8v a0 = *(const s8v*)(e0 + (size_t)s0 * DIM + c * 8);
    s8v a1 = *(const s8v*)(e1 + (size_t)s0 * DIM + c * 8);
    s8v b0 = *(const s8v*)(e0 + (size_t)s1 * DIM + c * 8);
    s8v b1 = *(const s8v*)(e1 + (size_t)s1 * DIM + c * 8);
    float4 o[2];
#pragma unroll
    for (int j = 0; j < 8; ++j) {
        float v = w0 * (bf2f(a0[j]) + bf2f(a1[j])) + w1 * (bf2f(b0[j]) + bf2f(b1[j]));
        ((float*)o)[j] = v;
    }
    float4* op = (float4*)(out + (size_t)t * DIM + c * 8);
    op[0] = o[0];
    op[1] = o[1];
}

extern "C" void kernel_launch(void* const* d_in, const int* in_sizes, int n_in,
                              void* d_out, int out_size, void* d_ws, size_t ws_size,
                              hipStream_t stream) {
    const float* x    = (const float*)d_in[0];
    const float* gw   = (const float*)d_in[1];
    const float* bias = (const float*)d_in[2];
    const float* w1   = (const float*)d_in[3];
    const float* w2   = (const float*)d_in[4];
    float* out = (float*)d_out;

    char* ws = (char*)d_ws;
    short* xb = (short*)ws;                           // 4 MiB  [T][DIM] bf16
    short* h  = (short*)(ws + (4ull << 20));          // 16 MiB [NSLOT][ED] bf16
    short* eo = (short*)(ws + (20ull << 20));         // 16 MiB [2][NSLOT][DIM] bf16
    char* meta = ws + (36ull << 20);
    int*   counts   = (int*)(meta);                   // [8]
    int*   offsets  = (int*)(meta + 64);              // [8]
    int*   tok_list = (int*)(meta + 128);             // [NSLOT]
    int*   slot_of  = (int*)(meta + 128 + 4 * NSLOT); // [T*2]
    int*   top2i    = (int*)(meta + 128 + 8 * NSLOT); // [T*2]
    float* top2w    = (float*)(meta + 128 + 8 * NSLOT + 8 * T);
    short* wb       = (short*)(ws + (37ull << 20));   // 32 MiB bf16 weight buffer (shared w1/w2)

    // need 37 MiB + 32 MiB for the bf16-weight path
    bool bf = ws_size >= (70ull << 20);

    hipMemsetAsync(counts, 0, 32, stream);

    // worst-case jobs per expert: mt<=16 -> ffn1 16*32=512, ffn2 16*16*2=512
    const int GRID_FFN1 = 8 * 16 * (ED / BN);           // 4096
    const int GRID_FFN2 = 8 * 16 * (DIM / BN) * KSPLIT; // 4096

    if (bf) {
        convert_kernel<<<2048, 256, 0, stream>>>(w1, wb, NE * ED * DIM / 8);
    }
    router_kernel<<<T / 4, 256, 0, stream>>>(x, gw, bias, xb, counts, top2i, top2w);
    plan_kernel<<<1, 256, 0, stream>>>(counts, top2i, offsets, tok_list, slot_of);
    if (bf) {
        ffn1_kernel<1><<<GRID_FFN1, 256, 0, stream>>>(xb, w1, wb, counts, offsets, tok_list, h);
        convert_kernel<<<2048, 256, 0, stream>>>(w2, wb, NE * DIM * ED / 8);
        ffn2_kernel<1><<<GRID_FFN2, 256, 0, stream>>>(h, w2, wb, counts, offsets, eo);
    } else {
        ffn1_kernel<0><<<GRID_FFN1, 256, 0, stream>>>(xb, w1, nullptr, counts, offsets, tok_list, h);
        ffn2_kernel<0><<<GRID_FFN2, 256, 0, stream>>>(h, w2, nullptr, counts, offsets, eo);
    }
    combine_kernel<<<T * DIM / 8 / 256, 256, 0, stream>>>(eo, slot_of, top2w, out);
}

// Round 7
// 345.055 us; speedup vs baseline: 1.1216x; 1.0067x over previous
//
#include <hip/hip_runtime.h>

#define T 2048
#define DIM 1024
#define NE 8
#define ED 2048
#define PSLOT 5120           // 4096 slots + per-expert pad-to-128 (<= 40 blocks of 128)
#define MT_MAX 16            // skew cap on m-tiles/expert (as all prior rounds)

#define BM 128
#define BN 64
#define BK 32

typedef __attribute__((ext_vector_type(8))) short s8v;   // 8 bf16 = 4 VGPRs
typedef __attribute__((ext_vector_type(4))) float f32x4; // MFMA C/D

__device__ __forceinline__ short f2bf(float f) {
    union { float f; unsigned u; } v;
    v.f = f;
    unsigned r = 0x7FFFu + ((v.u >> 16) & 1u);  // round-to-nearest-even
    v.u += r;
    return (short)(v.u >> 16);
}

__device__ __forceinline__ float bf2f(short s) {
    union { unsigned u; float f; } v;
    v.u = ((unsigned)(unsigned short)s) << 16;
    return v.f;
}

// pack two fp32 -> two bf16 (round-half-up) in 3 VALU
__device__ __forceinline__ unsigned pkbf2(float lo, float hi) {
    union { float f; unsigned u; } a, b;
    a.f = lo; b.f = hi;
    return __builtin_amdgcn_perm(b.u + 0x8000u, a.u + 0x8000u, 0x07060302u);
}

// async global->LDS: global src is PER-LANE, lds dst wave-uniform; lane i -> dst+16i
__device__ __forceinline__ void glds16(const void* g, void* l) {
    __builtin_amdgcn_global_load_lds(
        (const __attribute__((address_space(1))) void*)g,
        (__attribute__((address_space(3))) void*)l, 16, 0, 0);
}

// ---------------- convert w1 -> tiled bf16: [e][nb(32)][koct(128)][64][8] ----------------
__global__ __launch_bounds__(256) void convert1_kernel(const float* __restrict__ w1,
                                                       short* __restrict__ wbt) {
    int wid = blockIdx.x * 4 + (threadIdx.x >> 6);   // 8192 waves = 8*32*32
    int lane = threadIdx.x & 63;
    int e = wid >> 10, rem = wid & 1023, nb = rem >> 5, kk = rem & 31;
    const float4* src = (const float4*)(w1 + ((size_t)(e * ED + nb * 64 + lane)) * DIM + kk * 32);
    short* dst = wbt + ((size_t)(e * 32 + nb) * 128 + kk * 4) * 512 + lane * 8;
#pragma unroll
    for (int q = 0; q < 4; ++q) {
        float4 f0 = src[2 * q], f1 = src[2 * q + 1];
        uint4 o = { pkbf2(f0.x, f0.y), pkbf2(f0.z, f0.w), pkbf2(f1.x, f1.y), pkbf2(f1.z, f1.w) };
        *(uint4*)(dst + q * 512) = o;
    }
}

// ---------------- convert w2 -> tiled bf16: [e][nb(16)][koct(256)][64][8] ----------------
__global__ __launch_bounds__(256) void convert2_kernel(const float* __restrict__ w2,
                                                       short* __restrict__ wbt) {
    int wid = blockIdx.x * 4 + (threadIdx.x >> 6);   // 8192 waves = 8*16*64
    int lane = threadIdx.x & 63;
    int e = wid >> 10, rem = wid & 1023, nb = rem >> 6, kk = rem & 63;
    const float4* src = (const float4*)(w2 + ((size_t)(e * DIM + nb * 64 + lane)) * ED + kk * 32);
    short* dst = wbt + ((size_t)(e * 16 + nb) * 256 + kk * 4) * 512 + lane * 8;
#pragma unroll
    for (int q = 0; q < 4; ++q) {
        float4 f0 = src[2 * q], f1 = src[2 * q + 1];
        uint4 o = { pkbf2(f0.x, f0.y), pkbf2(f0.z, f0.w), pkbf2(f1.x, f1.y), pkbf2(f1.z, f1.w) };
        *(uint4*)(dst + q * 512) = o;
    }
}

// ---------------- router: 1 wave per token ----------------
__global__ void router_kernel(const float* __restrict__ x,
                              const float* __restrict__ gw,
                              const float* __restrict__ bias,
                              int* __restrict__ counts,
                              int* __restrict__ top2i,
                              float* __restrict__ top2w) {
    int wid = threadIdx.x >> 6;
    int lane = threadIdx.x & 63;
    int t = blockIdx.x * 4 + wid;

    const float* xr = x + (size_t)t * DIM + lane * 16;
    float4 xv[4];
#pragma unroll
    for (int j = 0; j < 4; ++j) xv[j] = *(const float4*)(xr + j * 4);

    float sc[NE];
#pragma unroll
    for (int e = 0; e < NE; ++e) {
        const float* gr = gw + e * DIM + lane * 16;
        float p = 0.f;
#pragma unroll
        for (int j = 0; j < 4; ++j) {
            float4 g = *(const float4*)(gr + j * 4);
            p += xv[j].x * g.x + xv[j].y * g.y + xv[j].z * g.z + xv[j].w * g.w;
        }
#pragma unroll
        for (int off = 32; off; off >>= 1) p += __shfl_xor(p, off, 64);
        sc[e] = 1.f / (1.f + __expf(-(p + bias[e])));
    }
    int b0 = 0; float s0 = sc[0];
#pragma unroll
    for (int e = 1; e < NE; ++e) if (sc[e] > s0) { s0 = sc[e]; b0 = e; }
    int b1 = -1; float s1 = -1e30f;
#pragma unroll
    for (int e = 0; e < NE; ++e) if (e != b0 && sc[e] > s1) { s1 = sc[e]; b1 = e; }
    float inv = 1.f / (s0 + s1 + 1e-6f);
    if (lane == 0) {
        top2i[t * 2 + 0] = b0; top2i[t * 2 + 1] = b1;
        top2w[t * 2 + 0] = s0 * inv; top2w[t * 2 + 1] = s1 * inv;
        atomicAdd(&counts[b0], 1);
        atomicAdd(&counts[b1], 1);
    }
}

// ---------------- plan: padded prefix + scatter + pad-fill ----------------
__global__ __launch_bounds__(256) void plan_kernel(
    const int* __restrict__ counts, const int* __restrict__ top2i,
    int* __restrict__ poff, int* __restrict__ tok_list, int* __restrict__ slot_of) {
    __shared__ int soff[NE];
    __shared__ int srun[NE];
    if (threadIdx.x == 0) {
        int a = 0;
        for (int e = 0; e < NE; ++e) {
            soff[e] = a; poff[e] = a;
            a += ((counts[e] + 127) >> 7) << 7;   // pad each expert region to 128
            srun[e] = 0;
        }
    }
    __syncthreads();
    for (int t = threadIdx.x; t < T; t += 256) {
#pragma unroll
        for (int k = 0; k < 2; ++k) {
            int e = top2i[t * 2 + k];
            int pos = atomicAdd(&srun[e], 1);
            int slot = soff[e] + pos;
            tok_list[slot] = t;
            slot_of[t * 2 + k] = slot;
        }
    }
    __syncthreads();
    for (int e = 0; e < NE; ++e) {
        int cnt = counts[e];
        int lim = ((cnt + 127) >> 7) << 7;
        for (int i = cnt + threadIdx.x; i < lim; i += 256) tok_list[soff[e] + i] = 0;
    }
}

// ---------------- gather: x (f32, token-scattered) -> xg_t tiled bf16 ----------------
// xg_t[pblk][koct(128)][128 rows][8]; block per (e, mblk); thread (r=tid&127, h=tid>>7).
__global__ __launch_bounds__(256) void gather_kernel(
    const float* __restrict__ x, const int* __restrict__ counts,
    const int* __restrict__ poff, const int* __restrict__ tok_list,
    short* __restrict__ xgt) {
    int e = blockIdx.x, mb = blockIdx.y;
    int cnt = counts[e];
    int mt = (cnt + 127) >> 7;
    if (mb >= mt) return;
    int pb = (poff[e] >> 7) + mb;
    int r = threadIdx.x & 127, hh = threadIdx.x >> 7;
    int tok = tok_list[poff[e] + mb * 128 + r];
    const float4* src = (const float4*)(x + (size_t)tok * DIM + hh * 16);
    short* dst = xgt + ((size_t)pb * 128 + hh * 2) * 1024 + r * 8;
#pragma unroll 4
    for (int kk = 0; kk < DIM / 32; ++kk) {
        float4 f0 = src[0], f1 = src[1], f2 = src[2], f3 = src[3];
        uint4 o0 = { pkbf2(f0.x, f0.y), pkbf2(f0.z, f0.w), pkbf2(f1.x, f1.y), pkbf2(f1.z, f1.w) };
        uint4 o1 = { pkbf2(f2.x, f2.y), pkbf2(f2.z, f2.w), pkbf2(f3.x, f3.y), pkbf2(f3.z, f3.w) };
        *(uint4*)(dst) = o0;
        *(uint4*)(dst + 1024) = o1;   // next koct chunk
        src += 8;          // +32 f32
        dst += 4 * 1024;   // +4 koct chunks
    }
}

// ---------------- grouped GEMM1: h_t = silu(xg_t @ w1_t^T), all staging coalesced ----------------
__global__ __launch_bounds__(256) void ffn1_kernel(
    const short* __restrict__ xgt, const short* __restrict__ wbt,
    const int* __restrict__ counts, const int* __restrict__ poff,
    short* __restrict__ ht) {
    int e = blockIdx.x & 7;
    int j = blockIdx.x >> 3;
    int cnt = counts[e];
    int mt = (cnt + 127) >> 7;
    const int NT = ED / BN;   // 32
    if (j >= mt * NT) return;
    int mb = j / NT, nb = j % NT;
    int pb = (poff[e] >> 7) + mb;

    __shared__ __align__(16) short As[2][4][BM][8];   // 16 KiB
    __shared__ __align__(16) short Bs[2][4][BN][8];   // 8 KiB

    int tid = threadIdx.x;
    int lane = tid & 63, w = tid >> 6;
    int mo = w * 32;
    int lrow = lane & 15, lq = lane >> 4;

    f32x4 acc[2][4];
#pragma unroll
    for (int mi = 0; mi < 2; ++mi)
#pragma unroll
        for (int ni = 0; ni < 4; ++ni) acc[mi][ni] = (f32x4){0.f, 0.f, 0.f, 0.f};

    const short* asrc = xgt + (size_t)pb * 128 * 1024;           // 128 koct chunks of 1024
    const short* bsrc = wbt + (size_t)(e * 32 + nb) * 128 * 512; // 128 koct chunks of 512

    // PER-LANE global src (+lane*8 shorts = 16B/lane); LDS dst wave-uniform.
    auto stage = [&](int s, int b) {
        int p = s * 4 + w;
        glds16(asrc + (size_t)p * 1024 + lane * 8,       &As[b][w][0][0]);
        glds16(asrc + (size_t)p * 1024 + 512 + lane * 8, &As[b][w][64][0]);
        glds16(bsrc + (size_t)p * 512 + lane * 8,        &Bs[b][w][0][0]);
    };
    const int NK = DIM / BK;   // 32
    stage(0, 0);
    for (int kk = 0; kk < NK; ++kk) {
        int cur = kk & 1, nxt = cur ^ 1;
        __syncthreads();   // buf[cur] landed everywhere
        if (kk + 1 < NK) stage(kk + 1, nxt);
        s8v af[2], bfr[4];
#pragma unroll
        for (int mi = 0; mi < 2; ++mi) af[mi] = *(const s8v*)&As[cur][lq][mo + mi * 16 + lrow][0];
#pragma unroll
        for (int ni = 0; ni < 4; ++ni) bfr[ni] = *(const s8v*)&Bs[cur][lq][ni * 16 + lrow][0];
#pragma unroll
        for (int mi = 0; mi < 2; ++mi)
#pragma unroll
            for (int ni = 0; ni < 4; ++ni)
                acc[mi][ni] = __builtin_amdgcn_mfma_f32_16x16x32_bf16(af[mi], bfr[ni], acc[mi][ni], 0, 0, 0);
    }

    int m0 = mb * 128;
#pragma unroll
    for (int mi = 0; mi < 2; ++mi) {
#pragma unroll
        for (int ni = 0; ni < 4; ++ni) {
            int ln = nb * 64 + ni * 16 + lrow;
            int koct = ln >> 3, jj = ln & 7;
#pragma unroll
            for (int r = 0; r < 4; ++r) {
                int lr = mo + mi * 16 + lq * 4 + r;
                if (m0 + lr < cnt) {
                    float v = acc[mi][ni][r];
                    v = v / (1.f + __expf(-v));  // silu
                    ht[((size_t)pb * 256 + koct) * 1024 + lr * 8 + jj] = f2bf(v);
                }
            }
        }
    }
}

// ---------------- grouped GEMM2: eo = h_t @ w2_t^T (full K, no split) ----------------
__global__ __launch_bounds__(256) void ffn2_kernel(
    const short* __restrict__ ht, const short* __restrict__ wbt,
    const int* __restrict__ counts, const int* __restrict__ poff,
    short* __restrict__ eo) {
    int e = blockIdx.x & 7;
    int j = blockIdx.x >> 3;
    int cnt = counts[e];
    int mt = (cnt + 127) >> 7;
    const int NT = DIM / BN;   // 16
    if (j >= mt * NT) return;
    int mb = j / NT, nb = j % NT;
    int pb = (poff[e] >> 7) + mb;

    __shared__ __align__(16) short As[2][4][BM][8];
    __shared__ __align__(16) short Bs[2][4][BN][8];

    int tid = threadIdx.x;
    int lane = tid & 63, w = tid >> 6;
    int mo = w * 32;
    int lrow = lane & 15, lq = lane >> 4;

    f32x4 acc[2][4];
#pragma unroll
    for (int mi = 0; mi < 2; ++mi)
#pragma unroll
        for (int ni = 0; ni < 4; ++ni) acc[mi][ni] = (f32x4){0.f, 0.f, 0.f, 0.f};

    const short* asrc = ht + (size_t)pb * 256 * 1024;            // 256 koct chunks of 1024
    const short* bsrc = wbt + (size_t)(e * 16 + nb) * 256 * 512; // 256 koct chunks of 512

    auto stage = [&](int s, int b) {
        int p = s * 4 + w;
        glds16(asrc + (size_t)p * 1024 + lane * 8,       &As[b][w][0][0]);
        glds16(asrc + (size_t)p * 1024 + 512 + lane * 8, &As[b][w][64][0]);
        glds16(bsrc + (size_t)p * 512 + lane * 8,        &Bs[b][w][0][0]);
    };
    const int NK = ED / BK;   // 64
    stage(0, 0);
    for (int kk = 0; kk < NK; ++kk) {
        int cur = kk & 1, nxt = cur ^ 1;
        __syncthreads();
        if (kk + 1 < NK) stage(kk + 1, nxt);
        s8v af[2], bfr[4];
#pragma unroll
        for (int mi = 0; mi < 2; ++mi) af[mi] = *(const s8v*)&As[cur][lq][mo + mi * 16 + lrow][0];
#pragma unroll
        for (int ni = 0; ni < 4; ++ni) bfr[ni] = *(const s8v*)&Bs[cur][lq][ni * 16 + lrow][0];
#pragma unroll
        for (int mi = 0; mi < 2; ++mi)
#pragma unroll
            for (int ni = 0; ni < 4; ++ni)
                acc[mi][ni] = __builtin_amdgcn_mfma_f32_16x16x32_bf16(af[mi], bfr[ni], acc[mi][ni], 0, 0, 0);
    }

    int m0 = mb * 128;
#pragma unroll
    for (int mi = 0; mi < 2; ++mi) {
#pragma unroll
        for (int ni = 0; ni < 4; ++ni) {
            int ln = nb * 64 + ni * 16 + lrow;
#pragma unroll
            for (int r = 0; r < 4; ++r) {
                int lr = mo + mi * 16 + lq * 4 + r;
                if (m0 + lr < cnt) {
                    eo[((size_t)pb * 128 + lr) * 1024 + ln] = f2bf(acc[mi][ni][r]);
                }
            }
        }
    }
}

// ---------------- combine ----------------
__global__ __launch_bounds__(256) void combine_kernel(
    const short* __restrict__ eo, const int* __restrict__ slot_of,
    const float* __restrict__ top2w, float* __restrict__ out) {
    int idx = blockIdx.x * 256 + threadIdx.x;
    int t = idx >> 7;
    int c = idx & 127;
    int s0 = slot_of[2 * t], s1 = slot_of[2 * t + 1];
    float w0 = top2w[2 * t], w1 = top2w[2 * t + 1];
    s8v a0 = *(const s8v*)(eo + (size_t)s0 * DIM + c * 8);
    s8v b0 = *(const s8v*)(eo + (size_t)s1 * DIM + c * 8);
    float4 o[2];
#pragma unroll
    for (int j = 0; j < 8; ++j) {
        float v = w0 * bf2f(a0[j]) + w1 * bf2f(b0[j]);
        ((float*)o)[j] = v;
    }
    float4* op = (float4*)(out + (size_t)t * DIM + c * 8);
    op[0] = o[0];
    op[1] = o[1];
}

extern "C" void kernel_launch(void* const* d_in, const int* in_sizes, int n_in,
                              void* d_out, int out_size, void* d_ws, size_t ws_size,
                              hipStream_t stream) {
    const float* x    = (const float*)d_in[0];
    const float* gw   = (const float*)d_in[1];
    const float* bias = (const float*)d_in[2];
    const float* w1   = (const float*)d_in[3];
    const float* w2   = (const float*)d_in[4];
    float* out = (float*)d_out;

    char* ws = (char*)d_ws;
    // xg_t: [40 pblk][128 koct][128][8] bf16 = 10 MiB; reused as eo [PSLOT][DIM] bf16 after ffn1
    short* xgt = (short*)ws;
    short* eo  = xgt;
    // h_t: [40 pblk][256 koct][128][8] bf16 = 20 MiB
    short* ht  = (short*)(ws + 10485760ull);
    char* meta = ws + 31457280ull;                    // metadata region
    int*   counts   = (int*)(meta);                   // [8]
    int*   poff     = (int*)(meta + 64);              // [8] padded offsets
    int*   tok_list = (int*)(meta + 128);             // [PSLOT]
    int*   slot_of  = (int*)(meta + 128 + 4 * PSLOT); // [T*2]
    int*   top2i    = (int*)(meta + 128 + 4 * PSLOT + 8 * T);
    float* top2w    = (float*)(meta + 128 + 4 * PSLOT + 16 * T);
    // wb: tiled bf16 weights, 32 MiB, shared sequentially by w1 then w2
    short* wbt = (short*)(ws + 33554432ull);          // ends at 64 MiB

    hipMemsetAsync(counts, 0, 32, stream);

    convert1_kernel<<<2048, 256, 0, stream>>>(w1, wbt);
    router_kernel<<<T / 4, 256, 0, stream>>>(x, gw, bias, counts, top2i, top2w);
    plan_kernel<<<1, 256, 0, stream>>>(counts, top2i, poff, tok_list, slot_of);
    gather_kernel<<<dim3(NE, MT_MAX), 256, 0, stream>>>(x, counts, poff, tok_list, xgt);
    ffn1_kernel<<<NE * MT_MAX * (ED / BN), 256, 0, stream>>>(xgt, wbt, counts, poff, ht);
    convert2_kernel<<<2048, 256, 0, stream>>>(w2, wbt);
    ffn2_kernel<<<NE * MT_MAX * (DIM / BN), 256, 0, stream>>>(ht, wbt, counts, poff, eo);
    combine_kernel<<<T * DIM / 8 / 256, 256, 0, stream>>>(eo, slot_of, top2w, out);
}

// Round 8
// 343.368 us; speedup vs baseline: 1.1271x; 1.0049x over previous
//
#include <hip/hip_runtime.h>

#define T 2048
#define DIM 1024
#define NE 8
#define ED 2048
#define PSLOT 5120           // 4096 slots + per-expert pad-to-128
#define MT_MAX 16            // skew cap on m-tiles/expert

#define BM 128
#define BN 128
#define BK 32

typedef __attribute__((ext_vector_type(8))) short s8v;   // 8 bf16 = 4 VGPRs
typedef __attribute__((ext_vector_type(4))) float f32x4; // MFMA C/D

__device__ __forceinline__ short f2bf(float f) {
    union { float f; unsigned u; } v;
    v.f = f;
    unsigned r = 0x7FFFu + ((v.u >> 16) & 1u);  // round-to-nearest-even
    v.u += r;
    return (short)(v.u >> 16);
}

__device__ __forceinline__ float bf2f(short s) {
    union { unsigned u; float f; } v;
    v.u = ((unsigned)(unsigned short)s) << 16;
    return v.f;
}

// pack two fp32 -> two bf16 (round-half-up) in 3 VALU
__device__ __forceinline__ unsigned pkbf2(float lo, float hi) {
    union { float f; unsigned u; } a, b;
    a.f = lo; b.f = hi;
    return __builtin_amdgcn_perm(b.u + 0x8000u, a.u + 0x8000u, 0x07060302u);
}

// async global->LDS: global src is PER-LANE, lds dst wave-uniform; lane i -> dst+16i
__device__ __forceinline__ void glds16(const void* g, void* l) {
    __builtin_amdgcn_global_load_lds(
        (const __attribute__((address_space(1))) void*)g,
        (__attribute__((address_space(3))) void*)l, 16, 0, 0);
}

// ---------------- convert w1 -> tiled bf16: [e][nb(16)][koct(128)][128][8] ----------------
// wave per (e, nb, half h, kk): lane = row within 64-row half; writes 4 koct chunks.
__global__ __launch_bounds__(256) void convert1_kernel(const float* __restrict__ w1,
                                                       short* __restrict__ wbt) {
    int wid = blockIdx.x * 4 + (threadIdx.x >> 6);   // 8192 waves = 8*16*2*32
    int lane = threadIdx.x & 63;
    int e = wid >> 10, rem = wid & 1023;
    int nb = rem >> 6, h = (rem >> 5) & 1, kk = rem & 31;
    const float4* src = (const float4*)(w1 + ((size_t)(e * ED + nb * 128 + h * 64 + lane)) * DIM + kk * 32);
    short* dst = wbt + ((size_t)(e * 16 + nb) * 128 + kk * 4) * 1024 + h * 512 + lane * 8;
#pragma unroll
    for (int q = 0; q < 4; ++q) {
        float4 f0 = src[2 * q], f1 = src[2 * q + 1];
        uint4 o = { pkbf2(f0.x, f0.y), pkbf2(f0.z, f0.w), pkbf2(f1.x, f1.y), pkbf2(f1.z, f1.w) };
        *(uint4*)(dst + q * 1024) = o;
    }
}

// ---------------- convert w2 -> tiled bf16: [e][nb(8)][koct(256)][128][8] ----------------
__global__ __launch_bounds__(256) void convert2_kernel(const float* __restrict__ w2,
                                                       short* __restrict__ wbt) {
    int wid = blockIdx.x * 4 + (threadIdx.x >> 6);   // 8192 waves = 8*8*2*64
    int lane = threadIdx.x & 63;
    int e = wid >> 10, rem = wid & 1023;
    int nb = rem >> 7, h = (rem >> 6) & 1, kk = rem & 63;
    const float4* src = (const float4*)(w2 + ((size_t)(e * DIM + nb * 128 + h * 64 + lane)) * ED + kk * 32);
    short* dst = wbt + ((size_t)(e * 8 + nb) * 256 + kk * 4) * 1024 + h * 512 + lane * 8;
#pragma unroll
    for (int q = 0; q < 4; ++q) {
        float4 f0 = src[2 * q], f1 = src[2 * q + 1];
        uint4 o = { pkbf2(f0.x, f0.y), pkbf2(f0.z, f0.w), pkbf2(f1.x, f1.y), pkbf2(f1.z, f1.w) };
        *(uint4*)(dst + q * 1024) = o;
    }
}

// ---------------- router: 1 wave per token ----------------
__global__ void router_kernel(const float* __restrict__ x,
                              const float* __restrict__ gw,
                              const float* __restrict__ bias,
                              int* __restrict__ counts,
                              int* __restrict__ top2i,
                              float* __restrict__ top2w) {
    int wid = threadIdx.x >> 6;
    int lane = threadIdx.x & 63;
    int t = blockIdx.x * 4 + wid;

    const float* xr = x + (size_t)t * DIM + lane * 16;
    float4 xv[4];
#pragma unroll
    for (int j = 0; j < 4; ++j) xv[j] = *(const float4*)(xr + j * 4);

    float sc[NE];
#pragma unroll
    for (int e = 0; e < NE; ++e) {
        const float* gr = gw + e * DIM + lane * 16;
        float p = 0.f;
#pragma unroll
        for (int j = 0; j < 4; ++j) {
            float4 g = *(const float4*)(gr + j * 4);
            p += xv[j].x * g.x + xv[j].y * g.y + xv[j].z * g.z + xv[j].w * g.w;
        }
#pragma unroll
        for (int off = 32; off; off >>= 1) p += __shfl_xor(p, off, 64);
        sc[e] = 1.f / (1.f + __expf(-(p + bias[e])));
    }
    int b0 = 0; float s0 = sc[0];
#pragma unroll
    for (int e = 1; e < NE; ++e) if (sc[e] > s0) { s0 = sc[e]; b0 = e; }
    int b1 = -1; float s1 = -1e30f;
#pragma unroll
    for (int e = 0; e < NE; ++e) if (e != b0 && sc[e] > s1) { s1 = sc[e]; b1 = e; }
    float inv = 1.f / (s0 + s1 + 1e-6f);
    if (lane == 0) {
        top2i[t * 2 + 0] = b0; top2i[t * 2 + 1] = b1;
        top2w[t * 2 + 0] = s0 * inv; top2w[t * 2 + 1] = s1 * inv;
        atomicAdd(&counts[b0], 1);
        atomicAdd(&counts[b1], 1);
    }
}

// ---------------- plan: padded prefix + scatter (tok + weight) + pad-fill ----------------
__global__ __launch_bounds__(256) void plan_kernel(
    const int* __restrict__ counts, const int* __restrict__ top2i,
    const float* __restrict__ top2w,
    int* __restrict__ poff, int* __restrict__ tok_list, float* __restrict__ slot_w) {
    __shared__ int soff[NE];
    __shared__ int srun[NE];
    if (threadIdx.x == 0) {
        int a = 0;
        for (int e = 0; e < NE; ++e) {
            soff[e] = a; poff[e] = a;
            a += ((counts[e] + 127) >> 7) << 7;   // pad each expert region to 128
            srun[e] = 0;
        }
    }
    __syncthreads();
    for (int t = threadIdx.x; t < T; t += 256) {
#pragma unroll
        for (int k = 0; k < 2; ++k) {
            int e = top2i[t * 2 + k];
            int pos = atomicAdd(&srun[e], 1);
            int slot = soff[e] + pos;
            tok_list[slot] = t;
            slot_w[slot] = top2w[t * 2 + k];
        }
    }
    __syncthreads();
    for (int e = 0; e < NE; ++e) {
        int cnt = counts[e];
        int lim = ((cnt + 127) >> 7) << 7;
        for (int i = cnt + threadIdx.x; i < lim; i += 256) {
            tok_list[soff[e] + i] = 0;
            slot_w[soff[e] + i] = 0.f;
        }
    }
}

// ---------------- gather: x (f32, token-scattered) -> xg_t tiled bf16 ----------------
// xg_t[pblk][koct(128)][128 rows][8]; block per (e, mblk); thread (r=tid&127, h=tid>>7).
__global__ __launch_bounds__(256) void gather_kernel(
    const float* __restrict__ x, const int* __restrict__ counts,
    const int* __restrict__ poff, const int* __restrict__ tok_list,
    short* __restrict__ xgt) {
    int e = blockIdx.x, mb = blockIdx.y;
    int cnt = counts[e];
    int mt = (cnt + 127) >> 7;
    if (mb >= mt) return;
    int pb = (poff[e] >> 7) + mb;
    int r = threadIdx.x & 127, hh = threadIdx.x >> 7;
    int tok = tok_list[poff[e] + mb * 128 + r];
    const float4* src = (const float4*)(x + (size_t)tok * DIM + hh * 16);
    short* dst = xgt + ((size_t)pb * 128 + hh * 2) * 1024 + r * 8;
#pragma unroll 4
    for (int kk = 0; kk < DIM / 32; ++kk) {
        float4 f0 = src[0], f1 = src[1], f2 = src[2], f3 = src[3];
        uint4 o0 = { pkbf2(f0.x, f0.y), pkbf2(f0.z, f0.w), pkbf2(f1.x, f1.y), pkbf2(f1.z, f1.w) };
        uint4 o1 = { pkbf2(f2.x, f2.y), pkbf2(f2.z, f2.w), pkbf2(f3.x, f3.y), pkbf2(f3.z, f3.w) };
        *(uint4*)(dst) = o0;
        *(uint4*)(dst + 1024) = o1;   // next koct chunk
        src += 8;          // +32 f32
        dst += 4 * 1024;   // +4 koct chunks
    }
}

// ---------------- grouped GEMM1: h_t = silu(xg_t @ w1_t^T); 128x128, coalesced glds ----------------
__global__ __launch_bounds__(256) void ffn1_kernel(
    const short* __restrict__ xgt, const short* __restrict__ wbt,
    const int* __restrict__ counts, const int* __restrict__ poff,
    short* __restrict__ ht) {
    int e = blockIdx.x & 7;
    int j = blockIdx.x >> 3;
    int cnt = counts[e];
    int mt = (cnt + 127) >> 7;
    const int NT = ED / BN;   // 16
    if (j >= mt * NT) return;
    int mb = j / NT, nb = j % NT;
    int pb = (poff[e] >> 7) + mb;

    __shared__ __align__(16) short As[2][4][BM][8];   // 16 KiB
    __shared__ __align__(16) short Bs[2][4][BN][8];   // 16 KiB

    int tid = threadIdx.x;
    int lane = tid & 63, w = tid >> 6;
    int mo = (w >> 1) * 64, no = (w & 1) * 64;
    int lrow = lane & 15, lq = lane >> 4;

    f32x4 acc[4][4];
#pragma unroll
    for (int mi = 0; mi < 4; ++mi)
#pragma unroll
        for (int ni = 0; ni < 4; ++ni) acc[mi][ni] = (f32x4){0.f, 0.f, 0.f, 0.f};

    const short* asrc = xgt + (size_t)pb * 128 * 1024;            // 128 koct chunks of 1024
    const short* bsrc = wbt + (size_t)(e * 16 + nb) * 128 * 1024; // 128 koct chunks of 1024

    // per-lane global src (16B/lane); wave w stages koct chunk kk*4+w of A and B
    auto stage = [&](int s, int b) {
        int p = s * 4 + w;
        glds16(asrc + (size_t)p * 1024 + lane * 8,       &As[b][w][0][0]);
        glds16(asrc + (size_t)p * 1024 + 512 + lane * 8, &As[b][w][64][0]);
        glds16(bsrc + (size_t)p * 1024 + lane * 8,       &Bs[b][w][0][0]);
        glds16(bsrc + (size_t)p * 1024 + 512 + lane * 8, &Bs[b][w][64][0]);
    };
    const int NK = DIM / BK;   // 32
    stage(0, 0);
    for (int kk = 0; kk < NK; ++kk) {
        int cur = kk & 1, nxt = cur ^ 1;
        __syncthreads();   // buf[cur] landed everywhere
        if (kk + 1 < NK) stage(kk + 1, nxt);
        s8v af[4], bfr[4];
#pragma unroll
        for (int mi = 0; mi < 4; ++mi) af[mi] = *(const s8v*)&As[cur][lq][mo + mi * 16 + lrow][0];
#pragma unroll
        for (int ni = 0; ni < 4; ++ni) bfr[ni] = *(const s8v*)&Bs[cur][lq][no + ni * 16 + lrow][0];
#pragma unroll
        for (int mi = 0; mi < 4; ++mi)
#pragma unroll
            for (int ni = 0; ni < 4; ++ni)
                acc[mi][ni] = __builtin_amdgcn_mfma_f32_16x16x32_bf16(af[mi], bfr[ni], acc[mi][ni], 0, 0, 0);
    }

    int m0 = mb * 128;
#pragma unroll
    for (int mi = 0; mi < 4; ++mi) {
#pragma unroll
        for (int ni = 0; ni < 4; ++ni) {
            int ln = nb * 128 + no + ni * 16 + lrow;
            int koct = ln >> 3, jj = ln & 7;
#pragma unroll
            for (int r = 0; r < 4; ++r) {
                int lr = mo + mi * 16 + lq * 4 + r;
                if (m0 + lr < cnt) {
                    float v = acc[mi][ni][r];
                    v = v / (1.f + __expf(-v));  // silu
                    ht[((size_t)pb * 256 + koct) * 1024 + lr * 8 + jj] = f2bf(v);
                }
            }
        }
    }
}

// ---------------- grouped GEMM2 (K-split, fused combine): out += w * (h_t @ w2_t^T) ----------------
__global__ __launch_bounds__(256) void ffn2_kernel(
    const short* __restrict__ ht, const short* __restrict__ wbt,
    const int* __restrict__ counts, const int* __restrict__ poff,
    const int* __restrict__ tok_list, const float* __restrict__ slot_w,
    float* __restrict__ out) {
    int e = blockIdx.x & 7;
    int j = blockIdx.x >> 3;
    int cnt = counts[e];
    int mt = (cnt + 127) >> 7;
    const int NT = DIM / BN;   // 8
    if (j >= mt * NT * 2) return;
    int ksp = j & 1; j >>= 1;
    int mb = j / NT, nb = j % NT;
    int pb = (poff[e] >> 7) + mb;

    __shared__ __align__(16) short As[2][4][BM][8];
    __shared__ __align__(16) short Bs[2][4][BN][8];

    int tid = threadIdx.x;
    int lane = tid & 63, w = tid >> 6;
    int mo = (w >> 1) * 64, no = (w & 1) * 64;
    int lrow = lane & 15, lq = lane >> 4;

    f32x4 acc[4][4];
#pragma unroll
    for (int mi = 0; mi < 4; ++mi)
#pragma unroll
        for (int ni = 0; ni < 4; ++ni) acc[mi][ni] = (f32x4){0.f, 0.f, 0.f, 0.f};

    const short* asrc = ht + ((size_t)pb * 256 + ksp * 128) * 1024;
    const short* bsrc = wbt + ((size_t)(e * 8 + nb) * 256 + ksp * 128) * 1024;

    auto stage = [&](int s, int b) {
        int p = s * 4 + w;
        glds16(asrc + (size_t)p * 1024 + lane * 8,       &As[b][w][0][0]);
        glds16(asrc + (size_t)p * 1024 + 512 + lane * 8, &As[b][w][64][0]);
        glds16(bsrc + (size_t)p * 1024 + lane * 8,       &Bs[b][w][0][0]);
        glds16(bsrc + (size_t)p * 1024 + 512 + lane * 8, &Bs[b][w][64][0]);
    };
    const int NK = (ED / 2) / BK;   // 32
    stage(0, 0);
    for (int kk = 0; kk < NK; ++kk) {
        int cur = kk & 1, nxt = cur ^ 1;
        __syncthreads();
        if (kk + 1 < NK) stage(kk + 1, nxt);
        s8v af[4], bfr[4];
#pragma unroll
        for (int mi = 0; mi < 4; ++mi) af[mi] = *(const s8v*)&As[cur][lq][mo + mi * 16 + lrow][0];
#pragma unroll
        for (int ni = 0; ni < 4; ++ni) bfr[ni] = *(const s8v*)&Bs[cur][lq][no + ni * 16 + lrow][0];
#pragma unroll
        for (int mi = 0; mi < 4; ++mi)
#pragma unroll
            for (int ni = 0; ni < 4; ++ni)
                acc[mi][ni] = __builtin_amdgcn_mfma_f32_16x16x32_bf16(af[mi], bfr[ni], acc[mi][ni], 0, 0, 0);
    }

    int m0 = mb * 128;
#pragma unroll
    for (int mi = 0; mi < 4; ++mi) {
#pragma unroll
        for (int r = 0; r < 4; ++r) {
            int lr = mo + mi * 16 + lq * 4 + r;
            if (m0 + lr < cnt) {
                int slot = poff[e] + m0 + lr;
                int t = tok_list[slot];
                float wv = slot_w[slot];
                float* orow = out + (size_t)t * DIM + nb * 128 + no + lrow;
#pragma unroll
                for (int ni = 0; ni < 4; ++ni)
                    atomicAdd(orow + ni * 16, wv * acc[mi][ni][r]);
            }
        }
    }
}

extern "C" void kernel_launch(void* const* d_in, const int* in_sizes, int n_in,
                              void* d_out, int out_size, void* d_ws, size_t ws_size,
                              hipStream_t stream) {
    const float* x    = (const float*)d_in[0];
    const float* gw   = (const float*)d_in[1];
    const float* bias = (const float*)d_in[2];
    const float* w1   = (const float*)d_in[3];
    const float* w2   = (const float*)d_in[4];
    float* out = (float*)d_out;

    char* ws = (char*)d_ws;
    // ht: [40 pblk][256 koct][128][8] bf16 = 20 MiB
    short* ht  = (short*)ws;
    // xg_t: [40 pblk][128 koct][128][8] bf16 = 10 MiB
    short* xgt = (short*)(ws + 20971520ull);
    char* meta = ws + 31457280ull;                    // metadata region
    int*   counts   = (int*)(meta);                   // [8]
    int*   poff     = (int*)(meta + 64);              // [8] padded offsets
    int*   tok_list = (int*)(meta + 128);             // [PSLOT]
    float* slot_w   = (float*)(meta + 128 + 4 * PSLOT); // [PSLOT]
    int*   top2i    = (int*)(meta + 128 + 8 * PSLOT);   // [T*2]
    float* top2w    = (float*)(meta + 128 + 8 * PSLOT + 8 * T);
    // wbt: tiled bf16 weights, 32 MiB, shared sequentially by w1 then w2
    short* wbt = (short*)(ws + 33554432ull);          // ends at 64 MiB

    hipMemsetAsync(counts, 0, 32, stream);
    hipMemsetAsync(out, 0, (size_t)T * DIM * 4, stream);   // ffn2 accumulates into out

    convert1_kernel<<<2048, 256, 0, stream>>>(w1, wbt);
    router_kernel<<<T / 4, 256, 0, stream>>>(x, gw, bias, counts, top2i, top2w);
    plan_kernel<<<1, 256, 0, stream>>>(counts, top2i, top2w, poff, tok_list, slot_w);
    gather_kernel<<<dim3(NE, MT_MAX), 256, 0, stream>>>(x, counts, poff, tok_list, xgt);
    ffn1_kernel<<<NE * MT_MAX * (ED / BN), 256, 0, stream>>>(xgt, wbt, counts, poff, ht);
    convert2_kernel<<<2048, 256, 0, stream>>>(w2, wbt);
    ffn2_kernel<<<NE * MT_MAX * (DIM / BN) * 2, 256, 0, stream>>>(ht, wbt, counts, poff, tok_list, slot_w, out);
}

// Round 9
// 295.887 us; speedup vs baseline: 1.3080x; 1.1605x over previous
//
#include <hip/hip_runtime.h>

#define T 2048
#define DIM 1024
#define NE 8
#define ED 2048
#define PSLOT 5120           // 4096 slots + per-expert pad-to-128
#define MT_MAX 16            // skew cap on m-tiles/expert

#define BM 128
#define BN 128
#define BK 32

typedef __attribute__((ext_vector_type(8))) short s8v;   // 8 bf16 = 4 VGPRs
typedef __attribute__((ext_vector_type(4))) float f32x4; // MFMA C/D

__device__ __forceinline__ short f2bf(float f) {
    union { float f; unsigned u; } v;
    v.f = f;
    unsigned r = 0x7FFFu + ((v.u >> 16) & 1u);  // round-to-nearest-even
    v.u += r;
    return (short)(v.u >> 16);
}

__device__ __forceinline__ float bf2f(short s) {
    union { unsigned u; float f; } v;
    v.u = ((unsigned)(unsigned short)s) << 16;
    return v.f;
}

// pack two fp32 -> two bf16 (round-half-up) in 3 VALU
__device__ __forceinline__ unsigned pkbf2(float lo, float hi) {
    union { float f; unsigned u; } a, b;
    a.f = lo; b.f = hi;
    return __builtin_amdgcn_perm(b.u + 0x8000u, a.u + 0x8000u, 0x07060302u);
}

// async global->LDS: global src is PER-LANE, lds dst wave-uniform; lane i -> dst+16i
__device__ __forceinline__ void glds16(const void* g, void* l) {
    __builtin_amdgcn_global_load_lds(
        (const __attribute__((address_space(1))) void*)g,
        (__attribute__((address_space(3))) void*)l, 16, 0, 0);
}

// ---------------- fused: convert w1 (blocks 0..2047) + router (blocks 2048..2559) ----------------
// convert: w1 -> tiled bf16 [e][nb(16)][koct(128)][128][8]
// router: scores only — NO global atomics (the 4096 RMWs on one L2 line were ~50 µs)
__global__ __launch_bounds__(256) void pre_kernel(
    const float* __restrict__ w1, short* __restrict__ wbt,
    const float* __restrict__ x, const float* __restrict__ gw,
    const float* __restrict__ bias,
    int* __restrict__ top2i, float* __restrict__ top2w) {
    if (blockIdx.x < 2048) {
        int wid = blockIdx.x * 4 + (threadIdx.x >> 6);   // 8192 waves = 8*16*2*32
        int lane = threadIdx.x & 63;
        int e = wid >> 10, rem = wid & 1023;
        int nb = rem >> 6, h = (rem >> 5) & 1, kk = rem & 31;
        const float4* src = (const float4*)(w1 + ((size_t)(e * ED + nb * 128 + h * 64 + lane)) * DIM + kk * 32);
        short* dst = wbt + ((size_t)(e * 16 + nb) * 128 + kk * 4) * 1024 + h * 512 + lane * 8;
#pragma unroll
        for (int q = 0; q < 4; ++q) {
            float4 f0 = src[2 * q], f1 = src[2 * q + 1];
            uint4 o = { pkbf2(f0.x, f0.y), pkbf2(f0.z, f0.w), pkbf2(f1.x, f1.y), pkbf2(f1.z, f1.w) };
            *(uint4*)(dst + q * 1024) = o;
        }
    } else {
        int wid = threadIdx.x >> 6;
        int lane = threadIdx.x & 63;
        int t = (blockIdx.x - 2048) * 4 + wid;

        const float* xr = x + (size_t)t * DIM + lane * 16;
        float4 xv[4];
#pragma unroll
        for (int j = 0; j < 4; ++j) xv[j] = *(const float4*)(xr + j * 4);

        float sc[NE];
#pragma unroll
        for (int e = 0; e < NE; ++e) {
            const float* gr = gw + e * DIM + lane * 16;
            float p = 0.f;
#pragma unroll
            for (int j = 0; j < 4; ++j) {
                float4 g = *(const float4*)(gr + j * 4);
                p += xv[j].x * g.x + xv[j].y * g.y + xv[j].z * g.z + xv[j].w * g.w;
            }
#pragma unroll
            for (int off = 32; off; off >>= 1) p += __shfl_xor(p, off, 64);
            sc[e] = 1.f / (1.f + __expf(-(p + bias[e])));
        }
        int b0 = 0; float s0 = sc[0];
#pragma unroll
        for (int e = 1; e < NE; ++e) if (sc[e] > s0) { s0 = sc[e]; b0 = e; }
        int b1 = -1; float s1 = -1e30f;
#pragma unroll
        for (int e = 0; e < NE; ++e) if (e != b0 && sc[e] > s1) { s1 = sc[e]; b1 = e; }
        float inv = 1.f / (s0 + s1 + 1e-6f);
        if (lane == 0) {
            top2i[t * 2 + 0] = b0; top2i[t * 2 + 1] = b1;
            top2w[t * 2 + 0] = s0 * inv; top2w[t * 2 + 1] = s1 * inv;
        }
    }
}

// ---------------- convert w2 -> tiled bf16: [e][nb(8)][koct(256)][128][8] ----------------
__global__ __launch_bounds__(256) void convert2_kernel(const float* __restrict__ w2,
                                                       short* __restrict__ wbt) {
    int wid = blockIdx.x * 4 + (threadIdx.x >> 6);   // 8192 waves = 8*8*2*64
    int lane = threadIdx.x & 63;
    int e = wid >> 10, rem = wid & 1023;
    int nb = rem >> 7, h = (rem >> 6) & 1, kk = rem & 63;
    const float4* src = (const float4*)(w2 + ((size_t)(e * DIM + nb * 128 + h * 64 + lane)) * ED + kk * 32);
    short* dst = wbt + ((size_t)(e * 8 + nb) * 256 + kk * 4) * 1024 + h * 512 + lane * 8;
#pragma unroll
    for (int q = 0; q < 4; ++q) {
        float4 f0 = src[2 * q], f1 = src[2 * q + 1];
        uint4 o = { pkbf2(f0.x, f0.y), pkbf2(f0.z, f0.w), pkbf2(f1.x, f1.y), pkbf2(f1.z, f1.w) };
        *(uint4*)(dst + q * 1024) = o;
    }
}

// ---------------- plan: LDS histogram + padded prefix + scatter + pad-fill ----------------
__global__ __launch_bounds__(256) void plan_kernel(
    const int* __restrict__ top2i, const float* __restrict__ top2w,
    int* __restrict__ counts, int* __restrict__ poff,
    int* __restrict__ tok_list, float* __restrict__ slot_w) {
    __shared__ int shist[NE];
    __shared__ int soff[NE];
    __shared__ int srun[NE];
    if (threadIdx.x < NE) { shist[threadIdx.x] = 0; srun[threadIdx.x] = 0; }
    __syncthreads();
    for (int i = threadIdx.x; i < 2 * T; i += 256) atomicAdd(&shist[top2i[i]], 1);
    __syncthreads();
    if (threadIdx.x == 0) {
        int a = 0;
        for (int e = 0; e < NE; ++e) {
            counts[e] = shist[e];
            poff[e] = a; soff[e] = a;
            a += ((shist[e] + 127) >> 7) << 7;   // pad each expert region to 128
        }
    }
    __syncthreads();
    for (int t = threadIdx.x; t < T; t += 256) {
#pragma unroll
        for (int k = 0; k < 2; ++k) {
            int e = top2i[t * 2 + k];
            int pos = atomicAdd(&srun[e], 1);
            int slot = soff[e] + pos;
            tok_list[slot] = t;
            slot_w[slot] = top2w[t * 2 + k];
        }
    }
    __syncthreads();
    for (int e = 0; e < NE; ++e) {
        int cnt = shist[e];
        int lim = ((cnt + 127) >> 7) << 7;
        for (int i = cnt + threadIdx.x; i < lim; i += 256) {
            tok_list[soff[e] + i] = 0;
            slot_w[soff[e] + i] = 0.f;
        }
    }
}

// ---------------- gather: x (f32, token-scattered) -> xg_t tiled bf16 ----------------
__global__ __launch_bounds__(256) void gather_kernel(
    const float* __restrict__ x, const int* __restrict__ counts,
    const int* __restrict__ poff, const int* __restrict__ tok_list,
    short* __restrict__ xgt) {
    int e = blockIdx.x, mb = blockIdx.y;
    int cnt = counts[e];
    int mt = (cnt + 127) >> 7;
    if (mb >= mt) return;
    int pb = (poff[e] >> 7) + mb;
    int r = threadIdx.x & 127, hh = threadIdx.x >> 7;
    int tok = tok_list[poff[e] + mb * 128 + r];
    const float4* src = (const float4*)(x + (size_t)tok * DIM + hh * 16);
    short* dst = xgt + ((size_t)pb * 128 + hh * 2) * 1024 + r * 8;
#pragma unroll 4
    for (int kk = 0; kk < DIM / 32; ++kk) {
        float4 f0 = src[0], f1 = src[1], f2 = src[2], f3 = src[3];
        uint4 o0 = { pkbf2(f0.x, f0.y), pkbf2(f0.z, f0.w), pkbf2(f1.x, f1.y), pkbf2(f1.z, f1.w) };
        uint4 o1 = { pkbf2(f2.x, f2.y), pkbf2(f2.z, f2.w), pkbf2(f3.x, f3.y), pkbf2(f3.z, f3.w) };
        *(uint4*)(dst) = o0;
        *(uint4*)(dst + 1024) = o1;   // next koct chunk
        src += 8;          // +32 f32
        dst += 4 * 1024;   // +4 koct chunks
    }
}

// ---------------- grouped GEMM1: h_t = silu(xg_t @ w1_t^T); 128x128, coalesced glds ----------------
__global__ __launch_bounds__(256) void ffn1_kernel(
    const short* __restrict__ xgt, const short* __restrict__ wbt,
    const int* __restrict__ counts, const int* __restrict__ poff,
    short* __restrict__ ht) {
    int e = blockIdx.x & 7;
    int j = blockIdx.x >> 3;
    int cnt = counts[e];
    int mt = (cnt + 127) >> 7;
    const int NT = ED / BN;   // 16
    if (j >= mt * NT) return;
    int mb = j / NT, nb = j % NT;
    int pb = (poff[e] >> 7) + mb;

    __shared__ __align__(16) short As[2][4][BM][8];   // 16 KiB
    __shared__ __align__(16) short Bs[2][4][BN][8];   // 16 KiB

    int tid = threadIdx.x;
    int lane = tid & 63, w = tid >> 6;
    int mo = (w >> 1) * 64, no = (w & 1) * 64;
    int lrow = lane & 15, lq = lane >> 4;

    f32x4 acc[4][4];
#pragma unroll
    for (int mi = 0; mi < 4; ++mi)
#pragma unroll
        for (int ni = 0; ni < 4; ++ni) acc[mi][ni] = (f32x4){0.f, 0.f, 0.f, 0.f};

    const short* asrc = xgt + (size_t)pb * 128 * 1024;            // 128 koct chunks of 1024
    const short* bsrc = wbt + (size_t)(e * 16 + nb) * 128 * 1024; // 128 koct chunks of 1024

    auto stage = [&](int s, int b) {
        int p = s * 4 + w;
        glds16(asrc + (size_t)p * 1024 + lane * 8,       &As[b][w][0][0]);
        glds16(asrc + (size_t)p * 1024 + 512 + lane * 8, &As[b][w][64][0]);
        glds16(bsrc + (size_t)p * 1024 + lane * 8,       &Bs[b][w][0][0]);
        glds16(bsrc + (size_t)p * 1024 + 512 + lane * 8, &Bs[b][w][64][0]);
    };
    const int NK = DIM / BK;   // 32
    stage(0, 0);
    for (int kk = 0; kk < NK; ++kk) {
        int cur = kk & 1, nxt = cur ^ 1;
        __syncthreads();   // buf[cur] landed everywhere
        if (kk + 1 < NK) stage(kk + 1, nxt);
        s8v af[4], bfr[4];
#pragma unroll
        for (int mi = 0; mi < 4; ++mi) af[mi] = *(const s8v*)&As[cur][lq][mo + mi * 16 + lrow][0];
#pragma unroll
        for (int ni = 0; ni < 4; ++ni) bfr[ni] = *(const s8v*)&Bs[cur][lq][no + ni * 16 + lrow][0];
#pragma unroll
        for (int mi = 0; mi < 4; ++mi)
#pragma unroll
            for (int ni = 0; ni < 4; ++ni)
                acc[mi][ni] = __builtin_amdgcn_mfma_f32_16x16x32_bf16(af[mi], bfr[ni], acc[mi][ni], 0, 0, 0);
    }

    int m0 = mb * 128;
#pragma unroll
    for (int mi = 0; mi < 4; ++mi) {
#pragma unroll
        for (int ni = 0; ni < 4; ++ni) {
            int ln = nb * 128 + no + ni * 16 + lrow;
            int koct = ln >> 3, jj = ln & 7;
#pragma unroll
            for (int r = 0; r < 4; ++r) {
                int lr = mo + mi * 16 + lq * 4 + r;
                if (m0 + lr < cnt) {
                    float v = acc[mi][ni][r];
                    v = v / (1.f + __expf(-v));  // silu
                    ht[((size_t)pb * 256 + koct) * 1024 + lr * 8 + jj] = f2bf(v);
                }
            }
        }
    }
}

// ---------------- grouped GEMM2 (K-split, fused combine): out += w * (h_t @ w2_t^T) ----------------
__global__ __launch_bounds__(256) void ffn2_kernel(
    const short* __restrict__ ht, const short* __restrict__ wbt,
    const int* __restrict__ counts, const int* __restrict__ poff,
    const int* __restrict__ tok_list, const float* __restrict__ slot_w,
    float* __restrict__ out) {
    int e = blockIdx.x & 7;
    int j = blockIdx.x >> 3;
    int cnt = counts[e];
    int mt = (cnt + 127) >> 7;
    const int NT = DIM / BN;   // 8
    if (j >= mt * NT * 2) return;
    int ksp = j & 1; j >>= 1;
    int mb = j / NT, nb = j % NT;
    int pb = (poff[e] >> 7) + mb;

    __shared__ __align__(16) short As[2][4][BM][8];
    __shared__ __align__(16) short Bs[2][4][BN][8];

    int tid = threadIdx.x;
    int lane = tid & 63, w = tid >> 6;
    int mo = (w >> 1) * 64, no = (w & 1) * 64;
    int lrow = lane & 15, lq = lane >> 4;

    f32x4 acc[4][4];
#pragma unroll
    for (int mi = 0; mi < 4; ++mi)
#pragma unroll
        for (int ni = 0; ni < 4; ++ni) acc[mi][ni] = (f32x4){0.f, 0.f, 0.f, 0.f};

    const short* asrc = ht + ((size_t)pb * 256 + ksp * 128) * 1024;
    const short* bsrc = wbt + ((size_t)(e * 8 + nb) * 256 + ksp * 128) * 1024;

    auto stage = [&](int s, int b) {
        int p = s * 4 + w;
        glds16(asrc + (size_t)p * 1024 + lane * 8,       &As[b][w][0][0]);
        glds16(asrc + (size_t)p * 1024 + 512 + lane * 8, &As[b][w][64][0]);
        glds16(bsrc + (size_t)p * 1024 + lane * 8,       &Bs[b][w][0][0]);
        glds16(bsrc + (size_t)p * 1024 + 512 + lane * 8, &Bs[b][w][64][0]);
    };
    const int NK = (ED / 2) / BK;   // 32
    stage(0, 0);
    for (int kk = 0; kk < NK; ++kk) {
        int cur = kk & 1, nxt = cur ^ 1;
        __syncthreads();
        if (kk + 1 < NK) stage(kk + 1, nxt);
        s8v af[4], bfr[4];
#pragma unroll
        for (int mi = 0; mi < 4; ++mi) af[mi] = *(const s8v*)&As[cur][lq][mo + mi * 16 + lrow][0];
#pragma unroll
        for (int ni = 0; ni < 4; ++ni) bfr[ni] = *(const s8v*)&Bs[cur][lq][no + ni * 16 + lrow][0];
#pragma unroll
        for (int mi = 0; mi < 4; ++mi)
#pragma unroll
            for (int ni = 0; ni < 4; ++ni)
                acc[mi][ni] = __builtin_amdgcn_mfma_f32_16x16x32_bf16(af[mi], bfr[ni], acc[mi][ni], 0, 0, 0);
    }

    int m0 = mb * 128;
#pragma unroll
    for (int mi = 0; mi < 4; ++mi) {
#pragma unroll
        for (int r = 0; r < 4; ++r) {
            int lr = mo + mi * 16 + lq * 4 + r;
            if (m0 + lr < cnt) {
                int slot = poff[e] + m0 + lr;
                int t = tok_list[slot];
                float wv = slot_w[slot];
                float* orow = out + (size_t)t * DIM + nb * 128 + no + lrow;
#pragma unroll
                for (int ni = 0; ni < 4; ++ni)
                    atomicAdd(orow + ni * 16, wv * acc[mi][ni][r]);
            }
        }
    }
}

extern "C" void kernel_launch(void* const* d_in, const int* in_sizes, int n_in,
                              void* d_out, int out_size, void* d_ws, size_t ws_size,
                              hipStream_t stream) {
    const float* x    = (const float*)d_in[0];
    const float* gw   = (const float*)d_in[1];
    const float* bias = (const float*)d_in[2];
    const float* w1   = (const float*)d_in[3];
    const float* w2   = (const float*)d_in[4];
    float* out = (float*)d_out;

    char* ws = (char*)d_ws;
    // ht: [40 pblk][256 koct][128][8] bf16 = 20 MiB
    short* ht  = (short*)ws;
    // xg_t: [40 pblk][128 koct][128][8] bf16 = 10 MiB
    short* xgt = (short*)(ws + 20971520ull);
    char* meta = ws + 31457280ull;                    // metadata region
    int*   counts   = (int*)(meta);                   // [8]
    int*   poff     = (int*)(meta + 64);              // [8] padded offsets
    int*   tok_list = (int*)(meta + 128);             // [PSLOT]
    float* slot_w   = (float*)(meta + 128 + 4 * PSLOT); // [PSLOT]
    int*   top2i    = (int*)(meta + 128 + 8 * PSLOT);   // [T*2]
    float* top2w    = (float*)(meta + 128 + 8 * PSLOT + 8 * T);
    // wbt: tiled bf16 weights, 32 MiB, shared sequentially by w1 then w2
    short* wbt = (short*)(ws + 33554432ull);          // ends at 64 MiB

    hipMemsetAsync(out, 0, (size_t)T * DIM * 4, stream);   // ffn2 accumulates into out

    pre_kernel<<<2048 + T / 4, 256, 0, stream>>>(w1, wbt, x, gw, bias, top2i, top2w);
    plan_kernel<<<1, 256, 0, stream>>>(top2i, top2w, counts, poff, tok_list, slot_w);
    gather_kernel<<<dim3(NE, MT_MAX), 256, 0, stream>>>(x, counts, poff, tok_list, xgt);
    ffn1_kernel<<<NE * MT_MAX * (ED / BN), 256, 0, stream>>>(xgt, wbt, counts, poff, ht);
    convert2_kernel<<<2048, 256, 0, stream>>>(w2, wbt);
    ffn2_kernel<<<NE * MT_MAX * (DIM / BN) * 2, 256, 0, stream>>>(ht, wbt, counts, poff, tok_list, slot_w, out);
}